// Round 1
// baseline (246.057 us; speedup 1.0000x reference)
//
#include <hip/hip_runtime.h>
#include <math.h>

// B=64, CLN=32, QL=32, IH=16, IW=16, IDF=8192, CDF=256, SL=128
// input : [64][32][32][16][16] fp32 ; context:[64][256][128] fp32 ; W:[8192][256] fp32
// out0: wc fp32 (16777216) ; out1: attnT [64][128][32] fp32 (262144)
//
// Zero-LDS MFMA pipeline, frag-major pre-swizzled operands.
// k1: fp16 hi/lo 3-pass, register double-buffered, 64m x 256n blocks (v2:
//     halved wave m-tile -> 512 blocks = 2 blocks/CU = 4 waves/SIMD), ZK=16.
// Order: k0a (Wth/Wtl) -> k1 -> k2 -> k0b (Wbf, overlaid) -> k3 -> k4.

#define ZK 16

typedef _Float16 f16x8 __attribute__((ext_vector_type(8)));
typedef float f32x4 __attribute__((ext_vector_type(4)));

// ---------------------------------------------------------------------------
// K0a: W -> Wth/Wtl (k1 B-operand hi/lo, frag-major). grid(256) x 256 thr.
// Frag addr: ((kb*16+nsub)*64 + lane)*8 ; lane=(c&15)+16*((k>>3)&3), j=k&7
// ---------------------------------------------------------------------------
__global__ __launch_bounds__(256) void k0a_prep(const float* __restrict__ Wm,
                                                _Float16* __restrict__ Wth,
                                                _Float16* __restrict__ Wtl) {
    const int kb = blockIdx.x;          // 0..255 (32 d-rows)
    const int t = threadIdx.x;
    __shared__ float tile[32][260];
    {
        const int r = t >> 3;           // 0..31
        const int c0 = (t & 7) * 32;    // 0..224
        const float* src = Wm + (long)(kb * 32 + r) * 256 + c0;
#pragma unroll
        for (int i = 0; i < 8; ++i) {
            float4 v = *(const float4*)(src + i * 4);
            tile[r][c0 + i * 4 + 0] = v.x;
            tile[r][c0 + i * 4 + 1] = v.y;
            tile[r][c0 + i * 4 + 2] = v.z;
            tile[r][c0 + i * 4 + 3] = v.w;
        }
    }
    __syncthreads();
    const int lane = t & 63;
    const int quad = lane >> 4, l15 = lane & 15;
#pragma unroll
    for (int i = 0; i < 4; ++i) {
        int nsub = (t >> 6) * 4 + i;    // 0..15
        f16x8 oh, ol;
#pragma unroll
        for (int j = 0; j < 8; ++j) {
            float f = tile[quad * 8 + j][nsub * 16 + l15];
            _Float16 h = (_Float16)f;
            oh[j] = h;
            ol[j] = (_Float16)(f - (float)h);
        }
        long addr = ((long)(kb * 16 + nsub) * 64 + lane) * 8;
        *(f16x8*)(Wth + addr) = oh;
        *(f16x8*)(Wtl + addr) = ol;
    }
}

// ---------------------------------------------------------------------------
// K0b: W -> Wbf (k4 A-operand fp16, frag-major). grid(1024) x 256 thr.
// Frag addr: ((mb*8+kb4)*64+lane)*8 ; lane=(d&15)+16*((c>>3)&3), j=c&7
// ---------------------------------------------------------------------------
__global__ __launch_bounds__(256) void k0b_prep(const float* __restrict__ Wm,
                                                _Float16* __restrict__ Wbf) {
    const int t = threadIdx.x;
    const int fid = blockIdx.x * 4 + (t >> 6);   // 0..4095
    const int mb = fid >> 3, kb4 = fid & 7;
    const int lane = t & 63;
    const int quad = lane >> 4, l15 = lane & 15;
    const float* src = Wm + (long)(mb * 16 + l15) * 256 + kb4 * 32 + quad * 8;
    float4 u0 = *(const float4*)(src);
    float4 u1 = *(const float4*)(src + 4);
    f16x8 o;
    o[0] = (_Float16)u0.x; o[1] = (_Float16)u0.y;
    o[2] = (_Float16)u0.z; o[3] = (_Float16)u0.w;
    o[4] = (_Float16)u1.x; o[5] = (_Float16)u1.y;
    o[6] = (_Float16)u1.z; o[7] = (_Float16)u1.w;
    *(f16x8*)(Wbf + ((long)fid * 64 + lane) * 8) = o;
}

// ---------------------------------------------------------------------------
// K1: tWpart = targetT @ W, fp16 hi/lo 3-pass, register double-buffered.
// v2: grid (32 m-tiles of 64, ZK=16) x 512 thr (8 waves, wave tile 32m x 64n).
// 512 blocks -> 2 blocks/CU -> 4 waves/SIMD (was 2). No LDS, no barriers.
// K per block = 512 (16 iters of BK=32). A still read exactly once (full-n block).
// ---------------------------------------------------------------------------
__global__ __launch_bounds__(512, 4) void k1_mfma(const float* __restrict__ inp,
                                                  const _Float16* __restrict__ Wth,
                                                  const _Float16* __restrict__ Wtl,
                                                  float* __restrict__ tWpart) {
    const int m0 = blockIdx.x * 64;
    const int kz = blockIdx.y;          // 0..15
    const int t = threadIdx.x;
    const int lane = t & 63, wv = t >> 6;
    const int quad = lane >> 4, l15 = lane & 15;
    const int mi = wv >> 2;             // 0..1 -> 2 m-frags each
    const int ni = wv & 3;              // 0..3 -> 4 n-frags each

    const float* arow0;
    const float* arow1;
    {
        int mA = m0 + (mi * 2 + 0) * 16 + l15;
        arow0 = inp + (long)(mA >> 5) * 262144 + (long)(mA & 31) * 256;
        mA = m0 + (mi * 2 + 1) * 16 + l15;
        arow1 = inp + (long)(mA >> 5) * 262144 + (long)(mA & 31) * 256;
    }

    f32x4 acc[2][4];
#pragma unroll
    for (int i = 0; i < 2; ++i)
#pragma unroll
        for (int j = 0; j < 4; ++j) acc[i][j] = (f32x4){0.f, 0.f, 0.f, 0.f};

    float4 Ar[2][2][2];
    f16x8 Bh[2][4], Bl[2][4];

    // prologue: load it=0
    {
        const int k0g = kz * 512;
        const long off = (long)(k0g >> 8) * 8192 + (k0g & 255) + quad * 8;
        Ar[0][0][0] = *(const float4*)(arow0 + off); Ar[0][0][1] = *(const float4*)(arow0 + off + 4);
        Ar[0][1][0] = *(const float4*)(arow1 + off); Ar[0][1][1] = *(const float4*)(arow1 + off + 4);
        const long base = ((long)((kz * 16) * 16 + ni * 4) * 64 + lane) * 8;
#pragma unroll
        for (int j = 0; j < 4; ++j) {
            Bh[0][j] = *(const f16x8*)(Wth + base + (long)j * 512);
            Bl[0][j] = *(const f16x8*)(Wtl + base + (long)j * 512);
        }
    }

#pragma unroll
    for (int it = 0; it < 16; ++it) {
        const int cur = it & 1, nxt = cur ^ 1;
        if (it < 15) {
            const int k0g = kz * 512 + (it + 1) * 32;
            const long off = (long)(k0g >> 8) * 8192 + (k0g & 255) + quad * 8;
            Ar[nxt][0][0] = *(const float4*)(arow0 + off); Ar[nxt][0][1] = *(const float4*)(arow0 + off + 4);
            Ar[nxt][1][0] = *(const float4*)(arow1 + off); Ar[nxt][1][1] = *(const float4*)(arow1 + off + 4);
            const long base = ((long)((kz * 16 + it + 1) * 16 + ni * 4) * 64 + lane) * 8;
#pragma unroll
            for (int j = 0; j < 4; ++j) {
                Bh[nxt][j] = *(const f16x8*)(Wth + base + (long)j * 512);
                Bl[nxt][j] = *(const f16x8*)(Wtl + base + (long)j * 512);
            }
        }
        f16x8 ah[2], al[2];
#pragma unroll
        for (int i = 0; i < 2; ++i) {
            float ff[8] = {Ar[cur][i][0].x, Ar[cur][i][0].y, Ar[cur][i][0].z, Ar[cur][i][0].w,
                           Ar[cur][i][1].x, Ar[cur][i][1].y, Ar[cur][i][1].z, Ar[cur][i][1].w};
#pragma unroll
            for (int j = 0; j < 8; ++j) {
                _Float16 h = (_Float16)ff[j];
                ah[i][j] = h;
                al[i][j] = (_Float16)(ff[j] - (float)h);
            }
        }
#pragma unroll
        for (int i = 0; i < 2; ++i)
#pragma unroll
            for (int j = 0; j < 4; ++j) {
                acc[i][j] = __builtin_amdgcn_mfma_f32_16x16x32_f16(ah[i], Bh[cur][j], acc[i][j], 0, 0, 0);
                acc[i][j] = __builtin_amdgcn_mfma_f32_16x16x32_f16(al[i], Bh[cur][j], acc[i][j], 0, 0, 0);
                acc[i][j] = __builtin_amdgcn_mfma_f32_16x16x32_f16(ah[i], Bl[cur][j], acc[i][j], 0, 0, 0);
            }
    }

    float* outp = tWpart + (long)kz * 524288;
#pragma unroll
    for (int i = 0; i < 2; ++i) {
        const int mbase = m0 + (mi * 2 + i) * 16 + quad * 4;
#pragma unroll
        for (int j = 0; j < 4; ++j) {
            const int c = (ni * 4 + j) * 16 + l15;
#pragma unroll
            for (int rg = 0; rg < 4; ++rg)
                outp[(long)(mbase + rg) * 256 + c] = acc[i][j][rg];
        }
    }
}

// ---------------------------------------------------------------------------
// K2: reduce split-K partials; logits = tW @ ctx[b]; softmax; write attnT.
// grid (8 q-groups of 4, 64 b) x 256 thr. One wave per q row.
// ---------------------------------------------------------------------------
__global__ __launch_bounds__(256) void k2_logits_softmax(const float* __restrict__ tWpart,
                                                         const float* __restrict__ ctx,
                                                         float* __restrict__ attnT) {
    const int qg = blockIdx.x;      // 0..7
    const int b  = blockIdx.y;
    const int t  = threadIdx.x;
    __shared__ float tw4[4][256];
#pragma unroll
    for (int qq = 0; qq < 4; ++qq) {
        const float* p = tWpart + (long)(b * 32 + qg * 4 + qq) * 256 + t;
        float s = 0.f;
#pragma unroll
        for (int z = 0; z < ZK; ++z) s += p[(long)z * 524288];
        tw4[qq][t] = s;
    }
    __syncthreads();
    const int q = t >> 6, lane = t & 63;
    const float* ctxb = ctx + (long)b * 32768 + lane * 2;
    float ax = 0.f, ay = 0.f;
#pragma unroll 4
    for (int c = 0; c < 256; ++c) {
        float tw = tw4[q][c];
        float2 cv = *(const float2*)(ctxb + c * 128);
        ax = fmaf(tw, cv.x, ax);
        ay = fmaf(tw, cv.y, ay);
    }
    float mx = fmaxf(ax, ay);
#pragma unroll
    for (int m = 1; m <= 32; m <<= 1) mx = fmaxf(mx, __shfl_xor(mx, m));
    float ex = expf(ax - mx);
    float ey = expf(ay - mx);
    float sm = ex + ey;
#pragma unroll
    for (int m = 1; m <= 32; m <<= 1) sm += __shfl_xor(sm, m);
    float inv = 1.f / sm;
    ex *= inv; ey *= inv;
    float* o = attnT + (long)b * 4096 + (qg * 4 + q);
    o[(lane * 2 + 0) * 32] = ex;
    o[(lane * 2 + 1) * 32] = ey;
}

// ---------------------------------------------------------------------------
// K3: ctxAqf (frag-major fp16) = ctx @ attn. grid (8 c-chunks, 64 b) x 256.
// Frag addr: [((n>>4)*8 + (c>>5))*64 + (n&15) + 16*((c>>3)&3)]*8 + (c&7)
// ---------------------------------------------------------------------------
__global__ __launch_bounds__(256) void k3_ctxA(const float* __restrict__ ctx,
                                               const float* __restrict__ attnT,
                                               _Float16* __restrict__ ctxAqf) {
    const int cg = blockIdx.x;      // c-chunk of 32
    const int b  = blockIdx.y;
    const int t  = threadIdx.x;
    __shared__ float at[128][32];
    __shared__ float cs[32][132];
#pragma unroll
    for (int i = 0; i < 4; ++i)
        *(float4*)((float*)at + i * 1024 + t * 4) =
            *(const float4*)(attnT + (long)b * 4096 + i * 1024 + t * 4);
#pragma unroll
    for (int i = 0; i < 4; ++i) {
        int idx = i * 256 + t;
        int c = idx >> 5, sseg = (idx & 31) * 4;
        *(float4*)&cs[c][sseg] = *(const float4*)(ctx + (long)b * 32768 + (long)(cg * 32 + c) * 128 + sseg);
    }
    __syncthreads();
    const int c = t >> 3;           // 0..31 (local)
    const int qs = (t & 7) * 4;     // 4 q's
    float4 acc = make_float4(0.f, 0.f, 0.f, 0.f);
#pragma unroll 4
    for (int s = 0; s < 128; ++s) {
        float cv = cs[c][s];
        float4 av = *(const float4*)&at[s][qs];
        acc.x = fmaf(cv, av.x, acc.x);
        acc.y = fmaf(cv, av.y, acc.y);
        acc.z = fmaf(cv, av.z, acc.z);
        acc.w = fmaf(cv, av.w, acc.w);
    }
    const int cglob = cg * 32 + c;
    const long cpart = (long)(cglob >> 5) * 64 + 16 * ((cglob >> 3) & 3);
    float vals[4] = {acc.x, acc.y, acc.z, acc.w};
#pragma unroll
    for (int u = 0; u < 4; ++u) {
        int n = b * 32 + qs + u;
        long addr = ((long)(n >> 4) * 8 * 64 + cpart + (n & 15)) * 8 + (cglob & 7);
        ctxAqf[addr] = (_Float16)vals[u];
    }
}

// ---------------------------------------------------------------------------
// K4: wc = W @ ctxA. No LDS. grid (128 m-tiles of 64, 16 n-tiles of 128) x 256.
// Wave tile: 16 m x 128 n. K=256 (8 kb of 32). .view-faithful scatter.
// ---------------------------------------------------------------------------
__global__ __launch_bounds__(256) void k4_mfma(const _Float16* __restrict__ Wbf,
                                               const _Float16* __restrict__ ctxAqf,
                                               float* __restrict__ out0) {
    const int t = threadIdx.x;
    const int lane = t & 63, wv = t >> 6;
    const int mb = blockIdx.x * 4 + wv;     // 0..511 (16 d-rows each)
    const int nb0 = blockIdx.y * 8;         // 8 nb groups of 16 n
    const _Float16* abase = Wbf + ((long)mb * 8 * 64 + lane) * 8;
    const _Float16* bbase = ctxAqf + ((long)nb0 * 8 * 64 + lane) * 8;

    f32x4 acc[8];
#pragma unroll
    for (int j = 0; j < 8; ++j) acc[j] = (f32x4){0.f, 0.f, 0.f, 0.f};

#pragma unroll
    for (int kb = 0; kb < 8; ++kb) {
        f16x8 af = *(const f16x8*)(abase + (long)kb * 512);
#pragma unroll
        for (int j = 0; j < 8; ++j) {
            f16x8 bf = *(const f16x8*)(bbase + (long)(j * 8 + kb) * 512);
            acc[j] = __builtin_amdgcn_mfma_f32_16x16x32_f16(af, bf, acc[j], 0, 0, 0);
        }
    }
    const int quad = lane >> 4, col = lane & 15;
#pragma unroll
    for (int j = 0; j < 8; ++j) {
        const int n = (nb0 + j) * 16 + col;
        float* ob = out0 + (long)(n >> 5) * 262144 + (n & 31);
#pragma unroll
        for (int rg = 0; rg < 4; ++rg) {
            const int d = mb * 16 + quad * 4 + rg;
            ob[(long)((d >> 3) & 31) * 8192 + (long)(d >> 8) * 256 + (long)(d & 7) * 32] = acc[j][rg];
        }
    }
}

// ---------------------------------------------------------------------------
extern "C" void kernel_launch(void* const* d_in, const int* in_sizes, int n_in,
                              void* d_out, int out_size, void* d_ws, size_t ws_size,
                              hipStream_t stream) {
    const float* inp = (const float*)d_in[0];
    const float* ctx = (const float*)d_in[1];
    const float* Wm  = (const float*)d_in[2];
    float* out0 = (float*)d_out;
    float* out1 = out0 + 16777216;

    // Workspace layout (40 MB peak):
    //   [0, 32 MB)   : tWpart (k1->k2); after k2, overlaid by Wbf (4 MB) + ctxAqf (1 MB)
    //   [32, 36 MB)  : Wth
    //   [36, 40 MB)  : Wtl
    float* wsf = (float*)d_ws;
    float* tWpart = wsf;                                   // 16*2048*256 floats = 32 MB
    _Float16* Wbf    = (_Float16*)wsf;                     // overlaid after k2 (4 MB)
    _Float16* ctxAqf = (_Float16*)(wsf + 1048576);         // overlaid after k2 (1 MB)
    _Float16* Wth = (_Float16*)(wsf + 8388608);            // 4 MB
    _Float16* Wtl = Wth + 2097152;                         // 4 MB

    hipLaunchKernelGGL(k0a_prep, dim3(256), dim3(256), 0, stream, Wm, Wth, Wtl);
    hipLaunchKernelGGL(k1_mfma, dim3(32, ZK), dim3(512), 0, stream, inp, Wth, Wtl, tWpart);
    hipLaunchKernelGGL(k2_logits_softmax, dim3(8, 64), dim3(256), 0, stream, tWpart, ctx, out1);
    hipLaunchKernelGGL(k0b_prep, dim3(1024), dim3(256), 0, stream, Wm, Wbf);
    hipLaunchKernelGGL(k3_ctxA, dim3(8, 64), dim3(256), 0, stream, ctx, out1, ctxAqf);
    hipLaunchKernelGGL(k4_mfma, dim3(128, 16), dim3(256), 0, stream, Wbf, ctxAqf, out0);
}

// Round 2
// 219.553 us; speedup vs baseline: 1.1207x; 1.1207x over previous
//
#include <hip/hip_runtime.h>
#include <math.h>

// B=64, CLN=32, QL=32, IH=16, IW=16, IDF=8192, CDF=256, SL=128
// input : [64][32][32][16][16] fp32 ; context:[64][256][128] fp32 ; W:[8192][256] fp32
// out0: wc fp32 (16777216) ; out1: attnT [64][128][32] fp32 (262144)
//
// Zero-LDS MFMA pipeline except k1, which is now LDS-staged:
// k1 v3: A staged via global_load_lds (async DMA, XOR-swizzled source),
//        B reg-prefetch pinned with sched_barrier, counted vmcnt(10) + raw
//        s_barrier (never vmcnt(0) in steady state). 128m x 256n blocks,
//        8 waves, wave tile 64x64, grid 16x16 (1 block/CU), ZK=16.
// Order: k0a (Wth/Wtl) -> k1 -> k2 -> k0b (Wbf, overlaid) -> k3 -> k4.

#define ZK 16

typedef _Float16 f16x8 __attribute__((ext_vector_type(8)));
typedef float f32x4 __attribute__((ext_vector_type(4)));

#define GLDS16(gp, lp)                                                          \
    __builtin_amdgcn_global_load_lds(                                           \
        (const __attribute__((address_space(1))) void*)(gp),                    \
        (__attribute__((address_space(3))) void*)(lp), 16, 0, 0)

// ---------------------------------------------------------------------------
// K0a: W -> Wth/Wtl (k1 B-operand hi/lo, frag-major). grid(256) x 256 thr.
// Frag addr: ((kb*16+nsub)*64 + lane)*8 ; lane=(c&15)+16*((k>>3)&3), j=k&7
// ---------------------------------------------------------------------------
__global__ __launch_bounds__(256) void k0a_prep(const float* __restrict__ Wm,
                                                _Float16* __restrict__ Wth,
                                                _Float16* __restrict__ Wtl) {
    const int kb = blockIdx.x;          // 0..255 (32 d-rows)
    const int t = threadIdx.x;
    __shared__ float tile[32][260];
    {
        const int r = t >> 3;           // 0..31
        const int c0 = (t & 7) * 32;    // 0..224
        const float* src = Wm + (long)(kb * 32 + r) * 256 + c0;
#pragma unroll
        for (int i = 0; i < 8; ++i) {
            float4 v = *(const float4*)(src + i * 4);
            tile[r][c0 + i * 4 + 0] = v.x;
            tile[r][c0 + i * 4 + 1] = v.y;
            tile[r][c0 + i * 4 + 2] = v.z;
            tile[r][c0 + i * 4 + 3] = v.w;
        }
    }
    __syncthreads();
    const int lane = t & 63;
    const int quad = lane >> 4, l15 = lane & 15;
#pragma unroll
    for (int i = 0; i < 4; ++i) {
        int nsub = (t >> 6) * 4 + i;    // 0..15
        f16x8 oh, ol;
#pragma unroll
        for (int j = 0; j < 8; ++j) {
            float f = tile[quad * 8 + j][nsub * 16 + l15];
            _Float16 h = (_Float16)f;
            oh[j] = h;
            ol[j] = (_Float16)(f - (float)h);
        }
        long addr = ((long)(kb * 16 + nsub) * 64 + lane) * 8;
        *(f16x8*)(Wth + addr) = oh;
        *(f16x8*)(Wtl + addr) = ol;
    }
}

// ---------------------------------------------------------------------------
// K0b: W -> Wbf (k4 A-operand fp16, frag-major). grid(1024) x 256 thr.
// Frag addr: ((mb*8+kb4)*64+lane)*8 ; lane=(d&15)+16*((c>>3)&3), j=c&7
// ---------------------------------------------------------------------------
__global__ __launch_bounds__(256) void k0b_prep(const float* __restrict__ Wm,
                                                _Float16* __restrict__ Wbf) {
    const int t = threadIdx.x;
    const int fid = blockIdx.x * 4 + (t >> 6);   // 0..4095
    const int mb = fid >> 3, kb4 = fid & 7;
    const int lane = t & 63;
    const int quad = lane >> 4, l15 = lane & 15;
    const float* src = Wm + (long)(mb * 16 + l15) * 256 + kb4 * 32 + quad * 8;
    float4 u0 = *(const float4*)(src);
    float4 u1 = *(const float4*)(src + 4);
    f16x8 o;
    o[0] = (_Float16)u0.x; o[1] = (_Float16)u0.y;
    o[2] = (_Float16)u0.z; o[3] = (_Float16)u0.w;
    o[4] = (_Float16)u1.x; o[5] = (_Float16)u1.y;
    o[6] = (_Float16)u1.z; o[7] = (_Float16)u1.w;
    *(f16x8*)(Wbf + ((long)fid * 64 + lane) * 8) = o;
}

// ---------------------------------------------------------------------------
// K1 v3: tWpart = targetT @ W, fp16 hi/lo 3-pass.
// grid (16 m-tiles of 128, ZK=16) x 512 thr (8 waves, wave tile 64m x 64n).
// A: LDS double-buffer [2][128][32] f32, staged by global_load_lds width=16.
//    XOR swizzle at 16B-chunk granularity: lds chunk c holds global chunk
//    c ^ (row&7). DMA dest stays linear (rule #21: swizzle source + read).
// B: frag-major fp16 hi/lo from L2, register double-buffered, pinned by
//    sched_barrier(0) so the compiler cannot sink the prefetch.
// Sync: counted s_waitcnt vmcnt(10) + raw s_barrier; barrier#2 after the
//    LDS reads protects the buffer against next iteration's DMA.
// ---------------------------------------------------------------------------
__global__ __launch_bounds__(512, 2) void k1_mfma(const float* __restrict__ inp,
                                                  const _Float16* __restrict__ Wth,
                                                  const _Float16* __restrict__ Wtl,
                                                  float* __restrict__ tWpart) {
    const int m0 = blockIdx.x * 128;
    const int kz = blockIdx.y;          // 0..15
    const int t = threadIdx.x;
    const int lane = t & 63, wv = t >> 6;
    const int quad = lane >> 4, l15 = lane & 15;
    const int mi = wv >> 2;             // 0..1 -> 4 m-frags each
    const int ni = wv & 3;              // 0..3 -> 4 n-frags each

    __shared__ float As[2][128][32];    // 32 KB

    // ---- staging addresses: thread t covers rows (t>>3) and (t>>3)+64,
    // dest 16B-chunk c4 = t&7, source chunk = c4 ^ (row&7) (row&7 same for both rows)
    const int srow = t >> 3;
    const int swc = ((t & 7) ^ (srow & 7)) * 4;   // float offset of source chunk
    const float* sb0;
    const float* sb1;
    {
        int mA = m0 + srow;
        sb0 = inp + (long)(mA >> 5) * 262144 + (long)(mA & 31) * 256 + swc;
        mA = m0 + 64 + srow;
        sb1 = inp + (long)(mA >> 5) * 262144 + (long)(mA & 31) * 256 + swc;
    }
    // wave-uniform LDS bases (HW adds lane*16B)
    float* lbase0 = &As[0][0][0] + wv * 256;      // rows 0..63 region
    float* lbase1 = &As[0][64][0] + wv * 256;     // rows 64..127 region
    float* lbase0b = &As[1][0][0] + wv * 256;
    float* lbase1b = &As[1][64][0] + wv * 256;

    f32x4 acc[4][4];
#pragma unroll
    for (int i = 0; i < 4; ++i)
#pragma unroll
        for (int j = 0; j < 4; ++j) acc[i][j] = (f32x4){0.f, 0.f, 0.f, 0.f};

    f16x8 Bh[2][4], Bl[2][4];

    // ---- prologue: issue stage(0) + B(0)  (10 VMEM in flight)
    {
        const int k0g = kz * 512;
        const long o = (long)(k0g >> 8) * 8192 + (k0g & 255);
        GLDS16(sb0 + o, lbase0);
        GLDS16(sb1 + o, lbase1);
        const long bb = ((long)((kz * 16) * 16 + ni * 4) * 64 + lane) * 8;
#pragma unroll
        for (int j = 0; j < 4; ++j) {
            Bh[0][j] = *(const f16x8*)(Wth + bb + (long)j * 512);
            Bl[0][j] = *(const f16x8*)(Wtl + bb + (long)j * 512);
        }
    }

#pragma unroll
    for (int it = 0; it < 16; ++it) {
        const int cur = it & 1, nxt = cur ^ 1;
        // (a)+(b): issue next tile's A-DMA and B reg-prefetch (10 VMEM)
        if (it < 15) {
            const int k0g = kz * 512 + (it + 1) * 32;
            const long o = (long)(k0g >> 8) * 8192 + (k0g & 255);
            if (nxt) { GLDS16(sb0 + o, lbase0b); GLDS16(sb1 + o, lbase1b); }
            else     { GLDS16(sb0 + o, lbase0);  GLDS16(sb1 + o, lbase1);  }
            const long bb = ((long)((kz * 16 + it + 1) * 16 + ni * 4) * 64 + lane) * 8;
#pragma unroll
            for (int j = 0; j < 4; ++j) {
                Bh[nxt][j] = *(const f16x8*)(Wth + bb + (long)j * 512);
                Bl[nxt][j] = *(const f16x8*)(Wtl + bb + (long)j * 512);
            }
        }
        __builtin_amdgcn_sched_barrier(0);
        // (c): wait for PREVIOUS batch (A(t) DMA + B(t)) — counted, not drain
        if (it < 15) asm volatile("s_waitcnt vmcnt(10)" ::: "memory");
        else         asm volatile("s_waitcnt vmcnt(0)" ::: "memory");
        __builtin_amdgcn_sched_barrier(0);
        __builtin_amdgcn_s_barrier();     // buf[cur] visible to all waves

        // (e): LDS -> regs, swizzled read, convert to fp16 hi/lo
        f16x8 ah[4], al[4];
#pragma unroll
        for (int i = 0; i < 4; ++i) {
            const int row = (mi * 4 + i) * 16 + l15;
            const int x = row & 7;
            float4 f0 = *(const float4*)&As[cur][row][((quad * 2) ^ x) * 4];
            float4 f1 = *(const float4*)&As[cur][row][((quad * 2 + 1) ^ x) * 4];
            float ff[8] = {f0.x, f0.y, f0.z, f0.w, f1.x, f1.y, f1.z, f1.w};
#pragma unroll
            for (int j = 0; j < 8; ++j) {
                _Float16 h = (_Float16)ff[j];
                ah[i][j] = h;
                al[i][j] = (_Float16)(ff[j] - (float)h);
            }
        }
        asm volatile("s_waitcnt lgkmcnt(0)" ::: "memory");
        __builtin_amdgcn_sched_barrier(0);
        __builtin_amdgcn_s_barrier();     // all waves done reading buf[cur]

        // (f): MFMA (register-only; overlaps other waves' staging)
#pragma unroll
        for (int i = 0; i < 4; ++i)
#pragma unroll
            for (int j = 0; j < 4; ++j) {
                acc[i][j] = __builtin_amdgcn_mfma_f32_16x16x32_f16(ah[i], Bh[cur][j], acc[i][j], 0, 0, 0);
                acc[i][j] = __builtin_amdgcn_mfma_f32_16x16x32_f16(al[i], Bh[cur][j], acc[i][j], 0, 0, 0);
                acc[i][j] = __builtin_amdgcn_mfma_f32_16x16x32_f16(ah[i], Bl[cur][j], acc[i][j], 0, 0, 0);
            }
    }

    float* outp = tWpart + (long)kz * 524288;
#pragma unroll
    for (int i = 0; i < 4; ++i) {
        const int mbase = m0 + (mi * 4 + i) * 16 + quad * 4;
#pragma unroll
        for (int j = 0; j < 4; ++j) {
            const int c = (ni * 4 + j) * 16 + l15;
#pragma unroll
            for (int rg = 0; rg < 4; ++rg)
                outp[(long)(mbase + rg) * 256 + c] = acc[i][j][rg];
        }
    }
}

// ---------------------------------------------------------------------------
// K2: reduce split-K partials; logits = tW @ ctx[b]; softmax; write attnT.
// grid (8 q-groups of 4, 64 b) x 256 thr. One wave per q row.
// ---------------------------------------------------------------------------
__global__ __launch_bounds__(256) void k2_logits_softmax(const float* __restrict__ tWpart,
                                                         const float* __restrict__ ctx,
                                                         float* __restrict__ attnT) {
    const int qg = blockIdx.x;      // 0..7
    const int b  = blockIdx.y;
    const int t  = threadIdx.x;
    __shared__ float tw4[4][256];
#pragma unroll
    for (int qq = 0; qq < 4; ++qq) {
        const float* p = tWpart + (long)(b * 32 + qg * 4 + qq) * 256 + t;
        float s = 0.f;
#pragma unroll
        for (int z = 0; z < ZK; ++z) s += p[(long)z * 524288];
        tw4[qq][t] = s;
    }
    __syncthreads();
    const int q = t >> 6, lane = t & 63;
    const float* ctxb = ctx + (long)b * 32768 + lane * 2;
    float ax = 0.f, ay = 0.f;
#pragma unroll 4
    for (int c = 0; c < 256; ++c) {
        float tw = tw4[q][c];
        float2 cv = *(const float2*)(ctxb + c * 128);
        ax = fmaf(tw, cv.x, ax);
        ay = fmaf(tw, cv.y, ay);
    }
    float mx = fmaxf(ax, ay);
#pragma unroll
    for (int m = 1; m <= 32; m <<= 1) mx = fmaxf(mx, __shfl_xor(mx, m));
    float ex = expf(ax - mx);
    float ey = expf(ay - mx);
    float sm = ex + ey;
#pragma unroll
    for (int m = 1; m <= 32; m <<= 1) sm += __shfl_xor(sm, m);
    float inv = 1.f / sm;
    ex *= inv; ey *= inv;
    float* o = attnT + (long)b * 4096 + (qg * 4 + q);
    o[(lane * 2 + 0) * 32] = ex;
    o[(lane * 2 + 1) * 32] = ey;
}

// ---------------------------------------------------------------------------
// K3: ctxAqf (frag-major fp16) = ctx @ attn. grid (8 c-chunks, 64 b) x 256.
// Frag addr: [((n>>4)*8 + (c>>5))*64 + (n&15) + 16*((c>>3)&3)]*8 + (c&7)
// ---------------------------------------------------------------------------
__global__ __launch_bounds__(256) void k3_ctxA(const float* __restrict__ ctx,
                                               const float* __restrict__ attnT,
                                               _Float16* __restrict__ ctxAqf) {
    const int cg = blockIdx.x;      // c-chunk of 32
    const int b  = blockIdx.y;
    const int t  = threadIdx.x;
    __shared__ float at[128][32];
    __shared__ float cs[32][132];
#pragma unroll
    for (int i = 0; i < 4; ++i)
        *(float4*)((float*)at + i * 1024 + t * 4) =
            *(const float4*)(attnT + (long)b * 4096 + i * 1024 + t * 4);
#pragma unroll
    for (int i = 0; i < 4; ++i) {
        int idx = i * 256 + t;
        int c = idx >> 5, sseg = (idx & 31) * 4;
        *(float4*)&cs[c][sseg] = *(const float4*)(ctx + (long)b * 32768 + (long)(cg * 32 + c) * 128 + sseg);
    }
    __syncthreads();
    const int c = t >> 3;           // 0..31 (local)
    const int qs = (t & 7) * 4;     // 4 q's
    float4 acc = make_float4(0.f, 0.f, 0.f, 0.f);
#pragma unroll 4
    for (int s = 0; s < 128; ++s) {
        float cv = cs[c][s];
        float4 av = *(const float4*)&at[s][qs];
        acc.x = fmaf(cv, av.x, acc.x);
        acc.y = fmaf(cv, av.y, acc.y);
        acc.z = fmaf(cv, av.z, acc.z);
        acc.w = fmaf(cv, av.w, acc.w);
    }
    const int cglob = cg * 32 + c;
    const long cpart = (long)(cglob >> 5) * 64 + 16 * ((cglob >> 3) & 3);
    float vals[4] = {acc.x, acc.y, acc.z, acc.w};
#pragma unroll
    for (int u = 0; u < 4; ++u) {
        int n = b * 32 + qs + u;
        long addr = ((long)(n >> 4) * 8 * 64 + cpart + (n & 15)) * 8 + (cglob & 7);
        ctxAqf[addr] = (_Float16)vals[u];
    }
}

// ---------------------------------------------------------------------------
// K4: wc = W @ ctxA. No LDS. grid (128 m-tiles of 64, 16 n-tiles of 128) x 256.
// Wave tile: 16 m x 128 n. K=256 (8 kb of 32). .view-faithful scatter.
// ---------------------------------------------------------------------------
__global__ __launch_bounds__(256) void k4_mfma(const _Float16* __restrict__ Wbf,
                                               const _Float16* __restrict__ ctxAqf,
                                               float* __restrict__ out0) {
    const int t = threadIdx.x;
    const int lane = t & 63, wv = t >> 6;
    const int mb = blockIdx.x * 4 + wv;     // 0..511 (16 d-rows each)
    const int nb0 = blockIdx.y * 8;         // 8 nb groups of 16 n
    const _Float16* abase = Wbf + ((long)mb * 8 * 64 + lane) * 8;
    const _Float16* bbase = ctxAqf + ((long)nb0 * 8 * 64 + lane) * 8;

    f32x4 acc[8];
#pragma unroll
    for (int j = 0; j < 8; ++j) acc[j] = (f32x4){0.f, 0.f, 0.f, 0.f};

#pragma unroll
    for (int kb = 0; kb < 8; ++kb) {
        f16x8 af = *(const f16x8*)(abase + (long)kb * 512);
#pragma unroll
        for (int j = 0; j < 8; ++j) {
            f16x8 bf = *(const f16x8*)(bbase + (long)(j * 8 + kb) * 512);
            acc[j] = __builtin_amdgcn_mfma_f32_16x16x32_f16(af, bf, acc[j], 0, 0, 0);
        }
    }
    const int quad = lane >> 4, col = lane & 15;
#pragma unroll
    for (int j = 0; j < 8; ++j) {
        const int n = (nb0 + j) * 16 + col;
        float* ob = out0 + (long)(n >> 5) * 262144 + (n & 31);
#pragma unroll
        for (int rg = 0; rg < 4; ++rg) {
            const int d = mb * 16 + quad * 4 + rg;
            ob[(long)((d >> 3) & 31) * 8192 + (long)(d >> 8) * 256 + (long)(d & 7) * 32] = acc[j][rg];
        }
    }
}

// ---------------------------------------------------------------------------
extern "C" void kernel_launch(void* const* d_in, const int* in_sizes, int n_in,
                              void* d_out, int out_size, void* d_ws, size_t ws_size,
                              hipStream_t stream) {
    const float* inp = (const float*)d_in[0];
    const float* ctx = (const float*)d_in[1];
    const float* Wm  = (const float*)d_in[2];
    float* out0 = (float*)d_out;
    float* out1 = out0 + 16777216;

    // Workspace layout (40 MB peak):
    //   [0, 32 MB)   : tWpart (k1->k2); after k2, overlaid by Wbf (4 MB) + ctxAqf (1 MB)
    //   [32, 36 MB)  : Wth
    //   [36, 40 MB)  : Wtl
    float* wsf = (float*)d_ws;
    float* tWpart = wsf;                                   // 16*2048*256 floats = 32 MB
    _Float16* Wbf    = (_Float16*)wsf;                     // overlaid after k2 (4 MB)
    _Float16* ctxAqf = (_Float16*)(wsf + 1048576);         // overlaid after k2 (1 MB)
    _Float16* Wth = (_Float16*)(wsf + 8388608);            // 4 MB
    _Float16* Wtl = Wth + 2097152;                         // 4 MB

    hipLaunchKernelGGL(k0a_prep, dim3(256), dim3(256), 0, stream, Wm, Wth, Wtl);
    hipLaunchKernelGGL(k1_mfma, dim3(16, ZK), dim3(512), 0, stream, inp, Wth, Wtl, tWpart);
    hipLaunchKernelGGL(k2_logits_softmax, dim3(8, 64), dim3(256), 0, stream, tWpart, ctx, out1);
    hipLaunchKernelGGL(k0b_prep, dim3(1024), dim3(256), 0, stream, Wm, Wbf);
    hipLaunchKernelGGL(k3_ctxA, dim3(8, 64), dim3(256), 0, stream, ctx, out1, ctxAqf);
    hipLaunchKernelGGL(k4_mfma, dim3(128, 16), dim3(256), 0, stream, Wbf, ctxAqf, out0);
}

// Round 3
// 218.189 us; speedup vs baseline: 1.1277x; 1.0062x over previous
//
#include <hip/hip_runtime.h>
#include <math.h>

// B=64, CLN=32, QL=32, IH=16, IW=16, IDF=8192, CDF=256, SL=128
// input : [64][32][32][16][16] fp32 ; context:[64][256][128] fp32 ; W:[8192][256] fp32
// out0: wc fp32 (16777216) ; out1: attnT [64][128][32] fp32 (262144)
//
// k1 v4: kz-locality block swizzle (2 kz/XCD -> B slice L2-resident),
//        A LDS triple-buffer staged 2 iters ahead via global_load_lds,
//        ONE raw s_barrier per iter, counted vmcnt(10) steady state.
// k4 v2: B-panel (64KB contiguous ctxAqf slice) staged to LDS once per block,
//        removing the 4x redundant per-wave L2 reads.
// Order: k0a (Wth/Wtl) -> k1 -> k2 -> k0b (Wbf, overlaid) -> k3 -> k4.

#define ZK 16

typedef _Float16 f16x8 __attribute__((ext_vector_type(8)));
typedef float f32x4 __attribute__((ext_vector_type(4)));

#define GLDS16(gp, lp)                                                          \
    __builtin_amdgcn_global_load_lds(                                           \
        (const __attribute__((address_space(1))) void*)(gp),                    \
        (__attribute__((address_space(3))) void*)(lp), 16, 0, 0)

// ---------------------------------------------------------------------------
// K0a: W -> Wth/Wtl (k1 B-operand hi/lo, frag-major). grid(256) x 256 thr.
// Frag addr: ((kb*16+nsub)*64 + lane)*8 ; lane=(c&15)+16*((k>>3)&3), j=k&7
// ---------------------------------------------------------------------------
__global__ __launch_bounds__(256) void k0a_prep(const float* __restrict__ Wm,
                                                _Float16* __restrict__ Wth,
                                                _Float16* __restrict__ Wtl) {
    const int kb = blockIdx.x;          // 0..255 (32 d-rows)
    const int t = threadIdx.x;
    __shared__ float tile[32][260];
    {
        const int r = t >> 3;           // 0..31
        const int c0 = (t & 7) * 32;    // 0..224
        const float* src = Wm + (long)(kb * 32 + r) * 256 + c0;
#pragma unroll
        for (int i = 0; i < 8; ++i) {
            float4 v = *(const float4*)(src + i * 4);
            tile[r][c0 + i * 4 + 0] = v.x;
            tile[r][c0 + i * 4 + 1] = v.y;
            tile[r][c0 + i * 4 + 2] = v.z;
            tile[r][c0 + i * 4 + 3] = v.w;
        }
    }
    __syncthreads();
    const int lane = t & 63;
    const int quad = lane >> 4, l15 = lane & 15;
#pragma unroll
    for (int i = 0; i < 4; ++i) {
        int nsub = (t >> 6) * 4 + i;    // 0..15
        f16x8 oh, ol;
#pragma unroll
        for (int j = 0; j < 8; ++j) {
            float f = tile[quad * 8 + j][nsub * 16 + l15];
            _Float16 h = (_Float16)f;
            oh[j] = h;
            ol[j] = (_Float16)(f - (float)h);
        }
        long addr = ((long)(kb * 16 + nsub) * 64 + lane) * 8;
        *(f16x8*)(Wth + addr) = oh;
        *(f16x8*)(Wtl + addr) = ol;
    }
}

// ---------------------------------------------------------------------------
// K0b: W -> Wbf (k4 A-operand fp16, frag-major). grid(1024) x 256 thr.
// Frag addr: ((mb*8+kb4)*64+lane)*8 ; lane=(d&15)+16*((c>>3)&3), j=c&7
// ---------------------------------------------------------------------------
__global__ __launch_bounds__(256) void k0b_prep(const float* __restrict__ Wm,
                                                _Float16* __restrict__ Wbf) {
    const int t = threadIdx.x;
    const int fid = blockIdx.x * 4 + (t >> 6);   // 0..4095
    const int mb = fid >> 3, kb4 = fid & 7;
    const int lane = t & 63;
    const int quad = lane >> 4, l15 = lane & 15;
    const float* src = Wm + (long)(mb * 16 + l15) * 256 + kb4 * 32 + quad * 8;
    float4 u0 = *(const float4*)(src);
    float4 u1 = *(const float4*)(src + 4);
    f16x8 o;
    o[0] = (_Float16)u0.x; o[1] = (_Float16)u0.y;
    o[2] = (_Float16)u0.z; o[3] = (_Float16)u0.w;
    o[4] = (_Float16)u1.x; o[5] = (_Float16)u1.y;
    o[6] = (_Float16)u1.z; o[7] = (_Float16)u1.w;
    *(f16x8*)(Wbf + ((long)fid * 64 + lane) * 8) = o;
}

// ---------------------------------------------------------------------------
// K1 v4: tWpart = targetT @ W, fp16 hi/lo 3-pass.
// grid 16x16 x 512 thr (8 waves, wave tile 64m x 64n), 1 block/CU.
// Block swizzle: lin = bx + 16*by; kz = lin&15, m0idx = lin>>4.
//   XCD = lin%8 -> each XCD sees kz in {c, c+8} only -> B slice (1 MB)
//   is XCD-L2-resident (was 8 MB spread -> L3 latency).
// A: LDS TRIPLE buffer [3][128][32] f32 staged 2 iters ahead by
//    global_load_lds w=16, XOR-swizzled source (rule #21).
// B: frag-major fp16 hi/lo, register double-buffer, 1 iter ahead
//    (compiler inserts the precise vmcnt before the MFMAs that use it).
// Sync per iter: s_waitcnt vmcnt(10) [waits A(t) only] -> s_barrier ->
//    issue A(t+2) DMA + B(t+1) -> ds_read A(t) -> MFMA(t). ONE barrier.
//    Race-free: passing barrier(t) proves all waves finished reading
//    As[(t-1)%3], the buffer DMA(t+2) overwrites.
// ---------------------------------------------------------------------------
__global__ __launch_bounds__(512, 2) void k1_mfma(const float* __restrict__ inp,
                                                  const _Float16* __restrict__ Wth,
                                                  const _Float16* __restrict__ Wtl,
                                                  float* __restrict__ tWpart) {
    const int lin = blockIdx.x + (blockIdx.y << 4);
    const int kz = lin & 15;            // 0..15 (2 distinct per XCD)
    const int m0 = (lin >> 4) * 128;
    const int t = threadIdx.x;
    const int lane = t & 63, wv = t >> 6;
    const int quad = lane >> 4, l15 = lane & 15;
    const int mi = wv >> 2;             // 0..1 -> 4 m-frags each
    const int ni = wv & 3;              // 0..3 -> 4 n-frags each

    __shared__ float As[3][128][32];    // 48 KB triple buffer

    // staging addresses: thread t covers rows (t>>3) and (t>>3)+64,
    // dest 16B-chunk = t&7, source chunk = (t&7) ^ (row&7)
    const int srow = t >> 3;
    const int swc = ((t & 7) ^ (srow & 7)) * 4;
    const float* sb0;
    const float* sb1;
    {
        int mA = m0 + srow;
        sb0 = inp + (long)(mA >> 5) * 262144 + (long)(mA & 31) * 256 + swc;
        mA = m0 + 64 + srow;
        sb1 = inp + (long)(mA >> 5) * 262144 + (long)(mA & 31) * 256 + swc;
    }

    f32x4 acc[4][4];
#pragma unroll
    for (int i = 0; i < 4; ++i)
#pragma unroll
        for (int j = 0; j < 4; ++j) acc[i][j] = (f32x4){0.f, 0.f, 0.f, 0.f};

    f16x8 Bh[2][4], Bl[2][4];

    // ---- prologue: DMA chunks 0,1 into buf 0,1; B(0) regs. 12 VMEM in flight.
    {
        long o = (long)((kz * 512) >> 8) * 8192 + ((kz * 512) & 255);
        GLDS16(sb0 + o, &As[0][0][0] + wv * 256);
        GLDS16(sb1 + o, &As[0][64][0] + wv * 256);
        const int k1g = kz * 512 + 32;
        o = (long)(k1g >> 8) * 8192 + (k1g & 255);
        GLDS16(sb0 + o, &As[1][0][0] + wv * 256);
        GLDS16(sb1 + o, &As[1][64][0] + wv * 256);
        const long bb = ((long)((kz * 16) * 16 + ni * 4) * 64 + lane) * 8;
#pragma unroll
        for (int j = 0; j < 4; ++j) {
            Bh[0][j] = *(const f16x8*)(Wth + bb + (long)j * 512);
            Bl[0][j] = *(const f16x8*)(Wtl + bb + (long)j * 512);
        }
    }

#pragma unroll
    for (int it = 0; it < 16; ++it) {
        const int cur = it & 1, nxt = cur ^ 1;
        // wait: newest 10 allowed = B(it)[8] + A(it+1)[2]  => A(it) complete
        if (it < 15) asm volatile("s_waitcnt vmcnt(10)" ::: "memory");
        else         asm volatile("s_waitcnt vmcnt(0)" ::: "memory");
        __builtin_amdgcn_sched_barrier(0);
        __builtin_amdgcn_s_barrier();     // all waves: A(it) staged, prev reads done
        __builtin_amdgcn_sched_barrier(0);

        // issue A(it+2) DMA and B(it+1) reg-prefetch (after barrier: race-free)
        if (it < 14) {
            const int kg = kz * 512 + (it + 2) * 32;
            const long o = (long)(kg >> 8) * 8192 + (kg & 255);
            GLDS16(sb0 + o, &As[(it + 2) % 3][0][0] + wv * 256);
            GLDS16(sb1 + o, &As[(it + 2) % 3][64][0] + wv * 256);
        }
        if (it < 15) {
            const long bb = ((long)((kz * 16 + it + 1) * 16 + ni * 4) * 64 + lane) * 8;
#pragma unroll
            for (int j = 0; j < 4; ++j) {
                Bh[nxt][j] = *(const f16x8*)(Wth + bb + (long)j * 512);
                Bl[nxt][j] = *(const f16x8*)(Wtl + bb + (long)j * 512);
            }
        }
        __builtin_amdgcn_sched_barrier(0);

        // LDS -> regs (swizzled read), convert to fp16 hi/lo
        f16x8 ah[4], al[4];
#pragma unroll
        for (int i = 0; i < 4; ++i) {
            const int row = (mi * 4 + i) * 16 + l15;
            const int x = row & 7;
            float4 f0 = *(const float4*)&As[it % 3][row][((quad * 2) ^ x) * 4];
            float4 f1 = *(const float4*)&As[it % 3][row][((quad * 2 + 1) ^ x) * 4];
            float ff[8] = {f0.x, f0.y, f0.z, f0.w, f1.x, f1.y, f1.z, f1.w};
#pragma unroll
            for (int j = 0; j < 8; ++j) {
                _Float16 h = (_Float16)ff[j];
                ah[i][j] = h;
                al[i][j] = (_Float16)(ff[j] - (float)h);
            }
        }

        // MFMA (register-only)
#pragma unroll
        for (int i = 0; i < 4; ++i)
#pragma unroll
            for (int j = 0; j < 4; ++j) {
                acc[i][j] = __builtin_amdgcn_mfma_f32_16x16x32_f16(ah[i], Bh[cur][j], acc[i][j], 0, 0, 0);
                acc[i][j] = __builtin_amdgcn_mfma_f32_16x16x32_f16(al[i], Bh[cur][j], acc[i][j], 0, 0, 0);
                acc[i][j] = __builtin_amdgcn_mfma_f32_16x16x32_f16(ah[i], Bl[cur][j], acc[i][j], 0, 0, 0);
            }
    }

    float* outp = tWpart + (long)kz * 524288;
#pragma unroll
    for (int i = 0; i < 4; ++i) {
        const int mbase = m0 + (mi * 4 + i) * 16 + quad * 4;
#pragma unroll
        for (int j = 0; j < 4; ++j) {
            const int c = (ni * 4 + j) * 16 + l15;
#pragma unroll
            for (int rg = 0; rg < 4; ++rg)
                outp[(long)(mbase + rg) * 256 + c] = acc[i][j][rg];
        }
    }
}

// ---------------------------------------------------------------------------
// K2: reduce split-K partials; logits = tW @ ctx[b]; softmax; write attnT.
// grid (8 q-groups of 4, 64 b) x 256 thr. One wave per q row.
// ---------------------------------------------------------------------------
__global__ __launch_bounds__(256) void k2_logits_softmax(const float* __restrict__ tWpart,
                                                         const float* __restrict__ ctx,
                                                         float* __restrict__ attnT) {
    const int qg = blockIdx.x;      // 0..7
    const int b  = blockIdx.y;
    const int t  = threadIdx.x;
    __shared__ float tw4[4][256];
#pragma unroll
    for (int qq = 0; qq < 4; ++qq) {
        const float* p = tWpart + (long)(b * 32 + qg * 4 + qq) * 256 + t;
        float s = 0.f;
#pragma unroll
        for (int z = 0; z < ZK; ++z) s += p[(long)z * 524288];
        tw4[qq][t] = s;
    }
    __syncthreads();
    const int q = t >> 6, lane = t & 63;
    const float* ctxb = ctx + (long)b * 32768 + lane * 2;
    float ax = 0.f, ay = 0.f;
#pragma unroll 4
    for (int c = 0; c < 256; ++c) {
        float tw = tw4[q][c];
        float2 cv = *(const float2*)(ctxb + c * 128);
        ax = fmaf(tw, cv.x, ax);
        ay = fmaf(tw, cv.y, ay);
    }
    float mx = fmaxf(ax, ay);
#pragma unroll
    for (int m = 1; m <= 32; m <<= 1) mx = fmaxf(mx, __shfl_xor(mx, m));
    float ex = expf(ax - mx);
    float ey = expf(ay - mx);
    float sm = ex + ey;
#pragma unroll
    for (int m = 1; m <= 32; m <<= 1) sm += __shfl_xor(sm, m);
    float inv = 1.f / sm;
    ex *= inv; ey *= inv;
    float* o = attnT + (long)b * 4096 + (qg * 4 + q);
    o[(lane * 2 + 0) * 32] = ex;
    o[(lane * 2 + 1) * 32] = ey;
}

// ---------------------------------------------------------------------------
// K3: ctxAqf (frag-major fp16) = ctx @ attn. grid (8 c-chunks, 64 b) x 256.
// Frag addr: [((n>>4)*8 + (c>>5))*64 + (n&15) + 16*((c>>3)&3)]*8 + (c&7)
// ---------------------------------------------------------------------------
__global__ __launch_bounds__(256) void k3_ctxA(const float* __restrict__ ctx,
                                               const float* __restrict__ attnT,
                                               _Float16* __restrict__ ctxAqf) {
    const int cg = blockIdx.x;      // c-chunk of 32
    const int b  = blockIdx.y;
    const int t  = threadIdx.x;
    __shared__ float at[128][32];
    __shared__ float cs[32][132];
#pragma unroll
    for (int i = 0; i < 4; ++i)
        *(float4*)((float*)at + i * 1024 + t * 4) =
            *(const float4*)(attnT + (long)b * 4096 + i * 1024 + t * 4);
#pragma unroll
    for (int i = 0; i < 4; ++i) {
        int idx = i * 256 + t;
        int c = idx >> 5, sseg = (idx & 31) * 4;
        *(float4*)&cs[c][sseg] = *(const float4*)(ctx + (long)b * 32768 + (long)(cg * 32 + c) * 128 + sseg);
    }
    __syncthreads();
    const int c = t >> 3;           // 0..31 (local)
    const int qs = (t & 7) * 4;     // 4 q's
    float4 acc = make_float4(0.f, 0.f, 0.f, 0.f);
#pragma unroll 4
    for (int s = 0; s < 128; ++s) {
        float cv = cs[c][s];
        float4 av = *(const float4*)&at[s][qs];
        acc.x = fmaf(cv, av.x, acc.x);
        acc.y = fmaf(cv, av.y, acc.y);
        acc.z = fmaf(cv, av.z, acc.z);
        acc.w = fmaf(cv, av.w, acc.w);
    }
    const int cglob = cg * 32 + c;
    const long cpart = (long)(cglob >> 5) * 64 + 16 * ((cglob >> 3) & 3);
    float vals[4] = {acc.x, acc.y, acc.z, acc.w};
#pragma unroll
    for (int u = 0; u < 4; ++u) {
        int n = b * 32 + qs + u;
        long addr = ((long)(n >> 4) * 8 * 64 + cpart + (n & 15)) * 8 + (cglob & 7);
        ctxAqf[addr] = (_Float16)vals[u];
    }
}

// ---------------------------------------------------------------------------
// K4 v2: wc = W @ ctxA. grid (128, 16) x 256 thr (4 waves).
// B-panel = 64 contiguous frags (64 KB) of ctxAqf, staged to LDS ONCE per
// block via global_load_lds (was: each of 4 waves re-read it from L2).
// 64 KB LDS -> 2 blocks/CU, staging of one block overlaps compute of other.
// Wave tile: 16 m x 128 n. K=256 (8 kb of 32). .view-faithful scatter.
// ---------------------------------------------------------------------------
__global__ __launch_bounds__(256) void k4_mfma(const _Float16* __restrict__ Wbf,
                                               const _Float16* __restrict__ ctxAqf,
                                               float* __restrict__ out0) {
    const int t = threadIdx.x;
    const int lane = t & 63, wv = t >> 6;
    const int mb = blockIdx.x * 4 + wv;     // 0..511 (16 d-rows each)
    const int nb0 = blockIdx.y * 8;         // 8 nb groups of 16 n

    __shared__ _Float16 Bs[32768];          // 64 KB: frags [nb0*8 .. nb0*8+64)

    // stage: 64 frags x 1 KB contiguous; 16 DMA insts per thread
    {
        const _Float16* gsrc = ctxAqf + (long)nb0 * 4096;   // frag nb0*8 * 512
#pragma unroll
        for (int i = 0; i < 16; ++i) {
            const int chunk = i * 256 + wv * 64;            // wave-uniform
            GLDS16(gsrc + (long)chunk * 8 + lane * 8, Bs + chunk * 8);
        }
    }
    __syncthreads();    // drains vmcnt(0): all DMAs visible to all waves

    const _Float16* abase = Wbf + ((long)mb * 8 * 64 + lane) * 8;

    f32x4 acc[8];
#pragma unroll
    for (int j = 0; j < 8; ++j) acc[j] = (f32x4){0.f, 0.f, 0.f, 0.f};

#pragma unroll
    for (int kb = 0; kb < 8; ++kb) {
        f16x8 af = *(const f16x8*)(abase + (long)kb * 512);
#pragma unroll
        for (int j = 0; j < 8; ++j) {
            f16x8 bf = *(const f16x8*)(Bs + (j * 8 + kb) * 512 + lane * 8);
            acc[j] = __builtin_amdgcn_mfma_f32_16x16x32_f16(af, bf, acc[j], 0, 0, 0);
        }
    }
    const int quad = lane >> 4, col = lane & 15;
#pragma unroll
    for (int j = 0; j < 8; ++j) {
        const int n = (nb0 + j) * 16 + col;
        float* ob = out0 + (long)(n >> 5) * 262144 + (n & 31);
#pragma unroll
        for (int rg = 0; rg < 4; ++rg) {
            const int d = mb * 16 + quad * 4 + rg;
            ob[(long)((d >> 3) & 31) * 8192 + (long)(d >> 8) * 256 + (long)(d & 7) * 32] = acc[j][rg];
        }
    }
}

// ---------------------------------------------------------------------------
extern "C" void kernel_launch(void* const* d_in, const int* in_sizes, int n_in,
                              void* d_out, int out_size, void* d_ws, size_t ws_size,
                              hipStream_t stream) {
    const float* inp = (const float*)d_in[0];
    const float* ctx = (const float*)d_in[1];
    const float* Wm  = (const float*)d_in[2];
    float* out0 = (float*)d_out;
    float* out1 = out0 + 16777216;

    // Workspace layout (40 MB peak):
    //   [0, 32 MB)   : tWpart (k1->k2); after k2, overlaid by Wbf (4 MB) + ctxAqf (1 MB)
    //   [32, 36 MB)  : Wth
    //   [36, 40 MB)  : Wtl
    float* wsf = (float*)d_ws;
    float* tWpart = wsf;                                   // 16*2048*256 floats = 32 MB
    _Float16* Wbf    = (_Float16*)wsf;                     // overlaid after k2 (4 MB)
    _Float16* ctxAqf = (_Float16*)(wsf + 1048576);         // overlaid after k2 (1 MB)
    _Float16* Wth = (_Float16*)(wsf + 8388608);            // 4 MB
    _Float16* Wtl = Wth + 2097152;                         // 4 MB

    hipLaunchKernelGGL(k0a_prep, dim3(256), dim3(256), 0, stream, Wm, Wth, Wtl);
    hipLaunchKernelGGL(k1_mfma, dim3(16, ZK), dim3(512), 0, stream, inp, Wth, Wtl, tWpart);
    hipLaunchKernelGGL(k2_logits_softmax, dim3(8, 64), dim3(256), 0, stream, tWpart, ctx, out1);
    hipLaunchKernelGGL(k0b_prep, dim3(1024), dim3(256), 0, stream, Wm, Wbf);
    hipLaunchKernelGGL(k3_ctxA, dim3(8, 64), dim3(256), 0, stream, ctx, out1, ctxAqf);
    hipLaunchKernelGGL(k4_mfma, dim3(128, 16), dim3(256), 0, stream, Wbf, ctxAqf, out0);
}

// Round 5
// 207.292 us; speedup vs baseline: 1.1870x; 1.0526x over previous
//
#include <hip/hip_runtime.h>
#include <math.h>

// B=64, CLN=32, QL=32, IH=16, IW=16, IDF=8192, CDF=256, SL=128
// input : [64][32][32][16][16] fp32 ; context:[64][256][128] fp32 ; W:[8192][256] fp32
// out0: wc fp32 (16777216) ; out1: attnT [64][128][32] fp32 (262144)
//
// k1 v5b: 256-thr blocks (4 waves), tile 64m x 256n, grid (16 kz, 32 m) =
//        512 blocks = 2 desynced blocks/CU. A: per-thread coalesced global
//        loads -> single cvt (pkrtz hi/lo) -> frag-major f16 LDS dbuf ->
//        ds_read_b128 frags. One s_barrier/iter. B: reg double-buffered
//        frag stream from L2 (kz%8 XCD-local). 3-pass fp16 hi/lo MFMA.
//        (v5 compile fix: cvt_pkrtz returns __fp16x2; bit-cast unions.)
// k4 v2: B-panel staged to LDS once per block.
// Order: k0a (Wth/Wtl) -> k1 -> k2 -> k0b (Wbf, overlaid) -> k3 -> k4.

#define ZK 16

typedef _Float16 f16x8 __attribute__((ext_vector_type(8)));
typedef __fp16 h16x2 __attribute__((ext_vector_type(2)));
typedef float f32x4 __attribute__((ext_vector_type(4)));

#define GLDS16(gp, lp)                                                          \
    __builtin_amdgcn_global_load_lds(                                           \
        (const __attribute__((address_space(1))) void*)(gp),                    \
        (__attribute__((address_space(3))) void*)(lp), 16, 0, 0)

// ---------------------------------------------------------------------------
// K0a: W -> Wth/Wtl (k1 B-operand hi/lo, frag-major). grid(256) x 256 thr.
// Frag addr: ((kb*16+nsub)*64 + lane)*8 ; lane=(c&15)+16*((k>>3)&3), j=k&7
// ---------------------------------------------------------------------------
__global__ __launch_bounds__(256) void k0a_prep(const float* __restrict__ Wm,
                                                _Float16* __restrict__ Wth,
                                                _Float16* __restrict__ Wtl) {
    const int kb = blockIdx.x;          // 0..255 (32 d-rows)
    const int t = threadIdx.x;
    __shared__ float tile[32][260];
    {
        const int r = t >> 3;           // 0..31
        const int c0 = (t & 7) * 32;    // 0..224
        const float* src = Wm + (long)(kb * 32 + r) * 256 + c0;
#pragma unroll
        for (int i = 0; i < 8; ++i) {
            float4 v = *(const float4*)(src + i * 4);
            tile[r][c0 + i * 4 + 0] = v.x;
            tile[r][c0 + i * 4 + 1] = v.y;
            tile[r][c0 + i * 4 + 2] = v.z;
            tile[r][c0 + i * 4 + 3] = v.w;
        }
    }
    __syncthreads();
    const int lane = t & 63;
    const int quad = lane >> 4, l15 = lane & 15;
#pragma unroll
    for (int i = 0; i < 4; ++i) {
        int nsub = (t >> 6) * 4 + i;    // 0..15
        f16x8 oh, ol;
#pragma unroll
        for (int j = 0; j < 8; ++j) {
            float f = tile[quad * 8 + j][nsub * 16 + l15];
            _Float16 h = (_Float16)f;
            oh[j] = h;
            ol[j] = (_Float16)(f - (float)h);
        }
        long addr = ((long)(kb * 16 + nsub) * 64 + lane) * 8;
        *(f16x8*)(Wth + addr) = oh;
        *(f16x8*)(Wtl + addr) = ol;
    }
}

// ---------------------------------------------------------------------------
// K0b: W -> Wbf (k4 A-operand fp16, frag-major). grid(1024) x 256 thr.
// Frag addr: ((mb*8+kb4)*64+lane)*8 ; lane=(d&15)+16*((c>>3)&3), j=c&7
// ---------------------------------------------------------------------------
__global__ __launch_bounds__(256) void k0b_prep(const float* __restrict__ Wm,
                                                _Float16* __restrict__ Wbf) {
    const int t = threadIdx.x;
    const int fid = blockIdx.x * 4 + (t >> 6);   // 0..4095
    const int mb = fid >> 3, kb4 = fid & 7;
    const int lane = t & 63;
    const int quad = lane >> 4, l15 = lane & 15;
    const float* src = Wm + (long)(mb * 16 + l15) * 256 + kb4 * 32 + quad * 8;
    float4 u0 = *(const float4*)(src);
    float4 u1 = *(const float4*)(src + 4);
    f16x8 o;
    o[0] = (_Float16)u0.x; o[1] = (_Float16)u0.y;
    o[2] = (_Float16)u0.z; o[3] = (_Float16)u0.w;
    o[4] = (_Float16)u1.x; o[5] = (_Float16)u1.y;
    o[6] = (_Float16)u1.z; o[7] = (_Float16)u1.w;
    *(f16x8*)(Wbf + ((long)fid * 64 + lane) * 8) = o;
}

// ---------------------------------------------------------------------------
// K1 v5b: tWpart = targetT @ W, fp16 hi/lo 3-pass.
// grid (16 kz, 32 m-tiles of 64) x 256 thr (4 waves; wave tile 64m x 64n).
// 512 blocks -> 2 independent blocks/CU (desynced phases overlap pipes).
// XCD = blockid%8 = kz%8 -> each XCD reads only 2 kz B-slices (L2-resident).
//
// Per iter (BK=32):
//   issue A(it+1) [2x b128 coalesced: 4 lanes/row cover 128B] and
//         B(it+1) [8x b128 frag loads]   (pinned by sched_barrier)
//   cvt A(it) regs -> hi/lo f16 (v_cvt_pkrtz, converted ONCE per element)
//   ds_write_b128 x2 into frag-major f16 dbuf (16 KB LDS)
//   lgkmcnt(0) ; s_barrier          (single barrier per iter)
//   ds_read_b128 x8 A-frags ; 48 MFMA in 3 independent passes
// Dbuf race-freedom: write(it+2)->buf[it&1] happens after barrier(it+1),
// which proves all waves consumed their reads(it) of buf[it&1].
// ---------------------------------------------------------------------------
__global__ __launch_bounds__(256, 2) void k1_mfma(const float* __restrict__ inp,
                                                  const _Float16* __restrict__ Wth,
                                                  const _Float16* __restrict__ Wtl,
                                                  float* __restrict__ tWpart) {
    const int kz = blockIdx.x;          // 0..15
    const int m0 = blockIdx.y * 64;     // 32 m-tiles of 64 rows
    const int t = threadIdx.x;
    const int lane = t & 63, wv = t >> 6;       // wv = n-slice owner (ni)
    const int quad = lane >> 4, l15 = lane & 15;

    // f16 A-frag double-buffer: [buf][m-frag 0..3][slot 0..63][8 halves] (hi, lo)
    __shared__ _Float16 Fh[2][4][64][8];    // 8 KB
    __shared__ _Float16 Fl[2][4][64][8];    // 8 KB

    // ---- A global addressing: thread covers row m0+(t>>2), k-quad t&3 (8 floats)
    const float* arow;
    {
        const int mA = m0 + (t >> 2);
        arow = inp + (long)(mA >> 5) * 262144 + (long)(mA & 31) * 256 + (t & 3) * 8;
    }
    // ---- ds_write slot: cell (frag = t>>6, slot = ((t&3)<<4) | ((t>>2)&15))
    _Float16* wh = &Fh[0][t >> 6][((t & 3) << 4) | ((t >> 2) & 15)][0];
    _Float16* wl = &Fl[0][t >> 6][((t & 3) << 4) | ((t >> 2) & 15)][0];

    f32x4 acc[4][4];
#pragma unroll
    for (int i = 0; i < 4; ++i)
#pragma unroll
        for (int j = 0; j < 4; ++j) acc[i][j] = (f32x4){0.f, 0.f, 0.f, 0.f};

    float4 Ar[2][2];
    f16x8 Bh[2][4], Bl[2][4];

    // ---- prologue: A(0), B(0)
    {
        const int kg = kz * 512;
        const long off = (long)(kg >> 8) * 8192 + (kg & 255);
        Ar[0][0] = *(const float4*)(arow + off);
        Ar[0][1] = *(const float4*)(arow + off + 4);
        const long bb = ((long)((kz * 16) * 16 + wv * 4) * 64 + lane) * 8;
#pragma unroll
        for (int j = 0; j < 4; ++j) {
            Bh[0][j] = *(const f16x8*)(Wth + bb + (long)j * 512);
            Bl[0][j] = *(const f16x8*)(Wtl + bb + (long)j * 512);
        }
    }

#pragma unroll
    for (int it = 0; it < 16; ++it) {
        const int cur = it & 1, nxt = cur ^ 1;
        // (a) issue next-iter A and B loads (prefetch; pinned below)
        if (it < 15) {
            const int kg = kz * 512 + (it + 1) * 32;
            const long off = (long)(kg >> 8) * 8192 + (kg & 255);
            Ar[nxt][0] = *(const float4*)(arow + off);
            Ar[nxt][1] = *(const float4*)(arow + off + 4);
            const long bb = ((long)((kz * 16 + it + 1) * 16 + wv * 4) * 64 + lane) * 8;
#pragma unroll
            for (int j = 0; j < 4; ++j) {
                Bh[nxt][j] = *(const f16x8*)(Wth + bb + (long)j * 512);
                Bl[nxt][j] = *(const f16x8*)(Wtl + bb + (long)j * 512);
            }
        }
        __builtin_amdgcn_sched_barrier(0);

        // (b) cvt A(it) -> packed hi/lo (pkrtz), converted once per element
        {
            const float4 a0 = Ar[cur][0], a1 = Ar[cur][1];
            h16x2 h01 = __builtin_amdgcn_cvt_pkrtz(a0.x, a0.y);
            h16x2 h23 = __builtin_amdgcn_cvt_pkrtz(a0.z, a0.w);
            h16x2 h45 = __builtin_amdgcn_cvt_pkrtz(a1.x, a1.y);
            h16x2 h67 = __builtin_amdgcn_cvt_pkrtz(a1.z, a1.w);
            h16x2 l01 = __builtin_amdgcn_cvt_pkrtz(a0.x - (float)h01[0], a0.y - (float)h01[1]);
            h16x2 l23 = __builtin_amdgcn_cvt_pkrtz(a0.z - (float)h23[0], a0.w - (float)h23[1]);
            h16x2 l45 = __builtin_amdgcn_cvt_pkrtz(a1.x - (float)h45[0], a1.y - (float)h45[1]);
            h16x2 l67 = __builtin_amdgcn_cvt_pkrtz(a1.z - (float)h67[0], a1.w - (float)h67[1]);
            union { f16x8 v; h16x2 p[4]; } H, L;
            H.p[0] = h01; H.p[1] = h23; H.p[2] = h45; H.p[3] = h67;
            L.p[0] = l01; L.p[1] = l23; L.p[2] = l45; L.p[3] = l67;
            *(f16x8*)(wh + cur * 2048) = H.v;   // ds_write_b128
            *(f16x8*)(wl + cur * 2048) = L.v;   // ds_write_b128
        }
        asm volatile("s_waitcnt lgkmcnt(0)" ::: "memory");
        __builtin_amdgcn_sched_barrier(0);
        __builtin_amdgcn_s_barrier();           // buf[cur] fully written
        __builtin_amdgcn_sched_barrier(0);

        // (c) A-frag reads + MFMA (3 independent passes)
        f16x8 ah[4], al[4];
#pragma unroll
        for (int i = 0; i < 4; ++i) {
            ah[i] = *(const f16x8*)&Fh[cur][i][lane][0];
            al[i] = *(const f16x8*)&Fl[cur][i][lane][0];
        }
#pragma unroll
        for (int i = 0; i < 4; ++i)
#pragma unroll
            for (int j = 0; j < 4; ++j)
                acc[i][j] = __builtin_amdgcn_mfma_f32_16x16x32_f16(ah[i], Bh[cur][j], acc[i][j], 0, 0, 0);
#pragma unroll
        for (int i = 0; i < 4; ++i)
#pragma unroll
            for (int j = 0; j < 4; ++j)
                acc[i][j] = __builtin_amdgcn_mfma_f32_16x16x32_f16(al[i], Bh[cur][j], acc[i][j], 0, 0, 0);
#pragma unroll
        for (int i = 0; i < 4; ++i)
#pragma unroll
            for (int j = 0; j < 4; ++j)
                acc[i][j] = __builtin_amdgcn_mfma_f32_16x16x32_f16(ah[i], Bl[cur][j], acc[i][j], 0, 0, 0);
    }

    float* outp = tWpart + (long)kz * 524288;
#pragma unroll
    for (int i = 0; i < 4; ++i) {
        const int mbase = m0 + i * 16 + quad * 4;
#pragma unroll
        for (int j = 0; j < 4; ++j) {
            const int c = (wv * 4 + j) * 16 + l15;
#pragma unroll
            for (int rg = 0; rg < 4; ++rg)
                outp[(long)(mbase + rg) * 256 + c] = acc[i][j][rg];
        }
    }
}

// ---------------------------------------------------------------------------
// K2: reduce split-K partials; logits = tW @ ctx[b]; softmax; write attnT.
// grid (8 q-groups of 4, 64 b) x 256 thr. One wave per q row.
// ---------------------------------------------------------------------------
__global__ __launch_bounds__(256) void k2_logits_softmax(const float* __restrict__ tWpart,
                                                         const float* __restrict__ ctx,
                                                         float* __restrict__ attnT) {
    const int qg = blockIdx.x;      // 0..7
    const int b  = blockIdx.y;
    const int t  = threadIdx.x;
    __shared__ float tw4[4][256];
#pragma unroll
    for (int qq = 0; qq < 4; ++qq) {
        const float* p = tWpart + (long)(b * 32 + qg * 4 + qq) * 256 + t;
        float s = 0.f;
#pragma unroll
        for (int z = 0; z < ZK; ++z) s += p[(long)z * 524288];
        tw4[qq][t] = s;
    }
    __syncthreads();
    const int q = t >> 6, lane = t & 63;
    const float* ctxb = ctx + (long)b * 32768 + lane * 2;
    float ax = 0.f, ay = 0.f;
#pragma unroll 4
    for (int c = 0; c < 256; ++c) {
        float tw = tw4[q][c];
        float2 cv = *(const float2*)(ctxb + c * 128);
        ax = fmaf(tw, cv.x, ax);
        ay = fmaf(tw, cv.y, ay);
    }
    float mx = fmaxf(ax, ay);
#pragma unroll
    for (int m = 1; m <= 32; m <<= 1) mx = fmaxf(mx, __shfl_xor(mx, m));
    float ex = expf(ax - mx);
    float ey = expf(ay - mx);
    float sm = ex + ey;
#pragma unroll
    for (int m = 1; m <= 32; m <<= 1) sm += __shfl_xor(sm, m);
    float inv = 1.f / sm;
    ex *= inv; ey *= inv;
    float* o = attnT + (long)b * 4096 + (qg * 4 + q);
    o[(lane * 2 + 0) * 32] = ex;
    o[(lane * 2 + 1) * 32] = ey;
}

// ---------------------------------------------------------------------------
// K3: ctxAqf (frag-major fp16) = ctx @ attn. grid (8 c-chunks, 64 b) x 256.
// Frag addr: [((n>>4)*8 + (c>>5))*64 + (n&15) + 16*((c>>3)&3)]*8 + (c&7)
// ---------------------------------------------------------------------------
__global__ __launch_bounds__(256) void k3_ctxA(const float* __restrict__ ctx,
                                               const float* __restrict__ attnT,
                                               _Float16* __restrict__ ctxAqf) {
    const int cg = blockIdx.x;      // c-chunk of 32
    const int b  = blockIdx.y;
    const int t  = threadIdx.x;
    __shared__ float at[128][32];
    __shared__ float cs[32][132];
#pragma unroll
    for (int i = 0; i < 4; ++i)
        *(float4*)((float*)at + i * 1024 + t * 4) =
            *(const float4*)(attnT + (long)b * 4096 + i * 1024 + t * 4);
#pragma unroll
    for (int i = 0; i < 4; ++i) {
        int idx = i * 256 + t;
        int c = idx >> 5, sseg = (idx & 31) * 4;
        *(float4*)&cs[c][sseg] = *(const float4*)(ctx + (long)b * 32768 + (long)(cg * 32 + c) * 128 + sseg);
    }
    __syncthreads();
    const int c = t >> 3;           // 0..31 (local)
    const int qs = (t & 7) * 4;     // 4 q's
    float4 acc = make_float4(0.f, 0.f, 0.f, 0.f);
#pragma unroll 4
    for (int s = 0; s < 128; ++s) {
        float cv = cs[c][s];
        float4 av = *(const float4*)&at[s][qs];
        acc.x = fmaf(cv, av.x, acc.x);
        acc.y = fmaf(cv, av.y, acc.y);
        acc.z = fmaf(cv, av.z, acc.z);
        acc.w = fmaf(cv, av.w, acc.w);
    }
    const int cglob = cg * 32 + c;
    const long cpart = (long)(cglob >> 5) * 64 + 16 * ((cglob >> 3) & 3);
    float vals[4] = {acc.x, acc.y, acc.z, acc.w};
#pragma unroll
    for (int u = 0; u < 4; ++u) {
        int n = b * 32 + qs + u;
        long addr = ((long)(n >> 4) * 8 * 64 + cpart + (n & 15)) * 8 + (cglob & 7);
        ctxAqf[addr] = (_Float16)vals[u];
    }
}

// ---------------------------------------------------------------------------
// K4 v2: wc = W @ ctxA. grid (128, 16) x 256 thr (4 waves).
// B-panel = 64 contiguous frags (64 KB) of ctxAqf, staged to LDS ONCE per
// block via global_load_lds. Wave tile: 16 m x 128 n. K=256 (8 kb of 32).
// ---------------------------------------------------------------------------
__global__ __launch_bounds__(256) void k4_mfma(const _Float16* __restrict__ Wbf,
                                               const _Float16* __restrict__ ctxAqf,
                                               float* __restrict__ out0) {
    const int t = threadIdx.x;
    const int lane = t & 63, wv = t >> 6;
    const int mb = blockIdx.x * 4 + wv;     // 0..511 (16 d-rows each)
    const int nb0 = blockIdx.y * 8;         // 8 nb groups of 16 n

    __shared__ _Float16 Bs[32768];          // 64 KB: frags [nb0*8 .. nb0*8+64)

    {
        const _Float16* gsrc = ctxAqf + (long)nb0 * 4096;
#pragma unroll
        for (int i = 0; i < 16; ++i) {
            const int chunk = i * 256 + wv * 64;            // wave-uniform
            GLDS16(gsrc + (long)chunk * 8 + lane * 8, Bs + chunk * 8);
        }
    }
    __syncthreads();

    const _Float16* abase = Wbf + ((long)mb * 8 * 64 + lane) * 8;

    f32x4 acc[8];
#pragma unroll
    for (int j = 0; j < 8; ++j) acc[j] = (f32x4){0.f, 0.f, 0.f, 0.f};

#pragma unroll
    for (int kb = 0; kb < 8; ++kb) {
        f16x8 af = *(const f16x8*)(abase + (long)kb * 512);
#pragma unroll
        for (int j = 0; j < 8; ++j) {
            f16x8 bf = *(const f16x8*)(Bs + (j * 8 + kb) * 512 + lane * 8);
            acc[j] = __builtin_amdgcn_mfma_f32_16x16x32_f16(af, bf, acc[j], 0, 0, 0);
        }
    }
    const int quad = lane >> 4, col = lane & 15;
#pragma unroll
    for (int j = 0; j < 8; ++j) {
        const int n = (nb0 + j) * 16 + col;
        float* ob = out0 + (long)(n >> 5) * 262144 + (n & 31);
#pragma unroll
        for (int rg = 0; rg < 4; ++rg) {
            const int d = mb * 16 + quad * 4 + rg;
            ob[(long)((d >> 3) & 31) * 8192 + (long)(d >> 8) * 256 + (long)(d & 7) * 32] = acc[j][rg];
        }
    }
}

// ---------------------------------------------------------------------------
extern "C" void kernel_launch(void* const* d_in, const int* in_sizes, int n_in,
                              void* d_out, int out_size, void* d_ws, size_t ws_size,
                              hipStream_t stream) {
    const float* inp = (const float*)d_in[0];
    const float* ctx = (const float*)d_in[1];
    const float* Wm  = (const float*)d_in[2];
    float* out0 = (float*)d_out;
    float* out1 = out0 + 16777216;

    // Workspace layout (40 MB peak):
    //   [0, 32 MB)   : tWpart (k1->k2); after k2, overlaid by Wbf (4 MB) + ctxAqf (1 MB)
    //   [32, 36 MB)  : Wth
    //   [36, 40 MB)  : Wtl
    float* wsf = (float*)d_ws;
    float* tWpart = wsf;                                   // 16*2048*256 floats = 32 MB
    _Float16* Wbf    = (_Float16*)wsf;                     // overlaid after k2 (4 MB)
    _Float16* ctxAqf = (_Float16*)(wsf + 1048576);         // overlaid after k2 (1 MB)
    _Float16* Wth = (_Float16*)(wsf + 8388608);            // 4 MB
    _Float16* Wtl = Wth + 2097152;                         // 4 MB

    hipLaunchKernelGGL(k0a_prep, dim3(256), dim3(256), 0, stream, Wm, Wth, Wtl);
    hipLaunchKernelGGL(k1_mfma, dim3(16, 32), dim3(256), 0, stream, inp, Wth, Wtl, tWpart);
    hipLaunchKernelGGL(k2_logits_softmax, dim3(8, 64), dim3(256), 0, stream, tWpart, ctx, out1);
    hipLaunchKernelGGL(k0b_prep, dim3(1024), dim3(256), 0, stream, Wm, Wbf);
    hipLaunchKernelGGL(k3_ctxA, dim3(8, 64), dim3(256), 0, stream, ctx, out1, ctxAqf);
    hipLaunchKernelGGL(k4_mfma, dim3(128, 16), dim3(256), 0, stream, Wbf, ctxAqf, out0);
}

// Round 6
// 196.439 us; speedup vs baseline: 1.2526x; 1.0552x over previous
//
#include <hip/hip_runtime.h>
#include <math.h>

// B=64, CLN=32, QL=32, IH=16, IW=16, IDF=8192, CDF=256, SL=128
// input : [64][32][32][16][16] fp32 ; context:[64][256][128] fp32 ; W:[8192][256] fp32
// out0: wc fp32 (16777216) ; out1: attnT [64][128][32] fp32 (262144)
//
// k1 v5b: 256-thr blocks (4 waves), tile 64m x 256n, grid (16 kz, 32 m) =
//        512 blocks = 2 desynced blocks/CU. A: per-thread coalesced global
//        loads -> single cvt (pkrtz hi/lo) -> frag-major f16 LDS dbuf ->
//        ds_read_b128 frags. One s_barrier/iter. B: reg double-buffered
//        frag stream from L2 (kz%8 XCD-local). 3-pass fp16 hi/lo MFMA.
// k2 v2: grid transposed to (64 b, 8 qg) so all 8 blocks of a batch share
//        one XCD-L2 (ctx[b] fetched once/XCD); float4 z-reduce; 4-chain
//        unroll-8 logits loop.
// k4 v2: B-panel staged to LDS once per block.
// Order: k0a (Wth/Wtl) -> k1 -> k2 -> k0b (Wbf, overlaid) -> k3 -> k4.

#define ZK 16

typedef _Float16 f16x8 __attribute__((ext_vector_type(8)));
typedef __fp16 h16x2 __attribute__((ext_vector_type(2)));
typedef float f32x4 __attribute__((ext_vector_type(4)));

#define GLDS16(gp, lp)                                                          \
    __builtin_amdgcn_global_load_lds(                                           \
        (const __attribute__((address_space(1))) void*)(gp),                    \
        (__attribute__((address_space(3))) void*)(lp), 16, 0, 0)

// ---------------------------------------------------------------------------
// K0a: W -> Wth/Wtl (k1 B-operand hi/lo, frag-major). grid(256) x 256 thr.
// Frag addr: ((kb*16+nsub)*64 + lane)*8 ; lane=(c&15)+16*((k>>3)&3), j=k&7
// ---------------------------------------------------------------------------
__global__ __launch_bounds__(256) void k0a_prep(const float* __restrict__ Wm,
                                                _Float16* __restrict__ Wth,
                                                _Float16* __restrict__ Wtl) {
    const int kb = blockIdx.x;          // 0..255 (32 d-rows)
    const int t = threadIdx.x;
    __shared__ float tile[32][260];
    {
        const int r = t >> 3;           // 0..31
        const int c0 = (t & 7) * 32;    // 0..224
        const float* src = Wm + (long)(kb * 32 + r) * 256 + c0;
#pragma unroll
        for (int i = 0; i < 8; ++i) {
            float4 v = *(const float4*)(src + i * 4);
            tile[r][c0 + i * 4 + 0] = v.x;
            tile[r][c0 + i * 4 + 1] = v.y;
            tile[r][c0 + i * 4 + 2] = v.z;
            tile[r][c0 + i * 4 + 3] = v.w;
        }
    }
    __syncthreads();
    const int lane = t & 63;
    const int quad = lane >> 4, l15 = lane & 15;
#pragma unroll
    for (int i = 0; i < 4; ++i) {
        int nsub = (t >> 6) * 4 + i;    // 0..15
        f16x8 oh, ol;
#pragma unroll
        for (int j = 0; j < 8; ++j) {
            float f = tile[quad * 8 + j][nsub * 16 + l15];
            _Float16 h = (_Float16)f;
            oh[j] = h;
            ol[j] = (_Float16)(f - (float)h);
        }
        long addr = ((long)(kb * 16 + nsub) * 64 + lane) * 8;
        *(f16x8*)(Wth + addr) = oh;
        *(f16x8*)(Wtl + addr) = ol;
    }
}

// ---------------------------------------------------------------------------
// K0b: W -> Wbf (k4 A-operand fp16, frag-major). grid(1024) x 256 thr.
// Frag addr: ((mb*8+kb4)*64+lane)*8 ; lane=(d&15)+16*((c>>3)&3), j=c&7
// ---------------------------------------------------------------------------
__global__ __launch_bounds__(256) void k0b_prep(const float* __restrict__ Wm,
                                                _Float16* __restrict__ Wbf) {
    const int t = threadIdx.x;
    const int fid = blockIdx.x * 4 + (t >> 6);   // 0..4095
    const int mb = fid >> 3, kb4 = fid & 7;
    const int lane = t & 63;
    const int quad = lane >> 4, l15 = lane & 15;
    const float* src = Wm + (long)(mb * 16 + l15) * 256 + kb4 * 32 + quad * 8;
    float4 u0 = *(const float4*)(src);
    float4 u1 = *(const float4*)(src + 4);
    f16x8 o;
    o[0] = (_Float16)u0.x; o[1] = (_Float16)u0.y;
    o[2] = (_Float16)u0.z; o[3] = (_Float16)u0.w;
    o[4] = (_Float16)u1.x; o[5] = (_Float16)u1.y;
    o[6] = (_Float16)u1.z; o[7] = (_Float16)u1.w;
    *(f16x8*)(Wbf + ((long)fid * 64 + lane) * 8) = o;
}

// ---------------------------------------------------------------------------
// K1 v5b: tWpart = targetT @ W, fp16 hi/lo 3-pass.
// grid (16 kz, 32 m-tiles of 64) x 256 thr (4 waves; wave tile 64m x 64n).
// ---------------------------------------------------------------------------
__global__ __launch_bounds__(256, 2) void k1_mfma(const float* __restrict__ inp,
                                                  const _Float16* __restrict__ Wth,
                                                  const _Float16* __restrict__ Wtl,
                                                  float* __restrict__ tWpart) {
    const int kz = blockIdx.x;          // 0..15
    const int m0 = blockIdx.y * 64;     // 32 m-tiles of 64 rows
    const int t = threadIdx.x;
    const int lane = t & 63, wv = t >> 6;       // wv = n-slice owner (ni)
    const int quad = lane >> 4, l15 = lane & 15;

    // f16 A-frag double-buffer: [buf][m-frag 0..3][slot 0..63][8 halves] (hi, lo)
    __shared__ _Float16 Fh[2][4][64][8];    // 8 KB
    __shared__ _Float16 Fl[2][4][64][8];    // 8 KB

    // ---- A global addressing: thread covers row m0+(t>>2), k-quad t&3 (8 floats)
    const float* arow;
    {
        const int mA = m0 + (t >> 2);
        arow = inp + (long)(mA >> 5) * 262144 + (long)(mA & 31) * 256 + (t & 3) * 8;
    }
    // ---- ds_write slot: cell (frag = t>>6, slot = ((t&3)<<4) | ((t>>2)&15))
    _Float16* wh = &Fh[0][t >> 6][((t & 3) << 4) | ((t >> 2) & 15)][0];
    _Float16* wl = &Fl[0][t >> 6][((t & 3) << 4) | ((t >> 2) & 15)][0];

    f32x4 acc[4][4];
#pragma unroll
    for (int i = 0; i < 4; ++i)
#pragma unroll
        for (int j = 0; j < 4; ++j) acc[i][j] = (f32x4){0.f, 0.f, 0.f, 0.f};

    float4 Ar[2][2];
    f16x8 Bh[2][4], Bl[2][4];

    // ---- prologue: A(0), B(0)
    {
        const int kg = kz * 512;
        const long off = (long)(kg >> 8) * 8192 + (kg & 255);
        Ar[0][0] = *(const float4*)(arow + off);
        Ar[0][1] = *(const float4*)(arow + off + 4);
        const long bb = ((long)((kz * 16) * 16 + wv * 4) * 64 + lane) * 8;
#pragma unroll
        for (int j = 0; j < 4; ++j) {
            Bh[0][j] = *(const f16x8*)(Wth + bb + (long)j * 512);
            Bl[0][j] = *(const f16x8*)(Wtl + bb + (long)j * 512);
        }
    }

#pragma unroll
    for (int it = 0; it < 16; ++it) {
        const int cur = it & 1, nxt = cur ^ 1;
        // (a) issue next-iter A and B loads (prefetch; pinned below)
        if (it < 15) {
            const int kg = kz * 512 + (it + 1) * 32;
            const long off = (long)(kg >> 8) * 8192 + (kg & 255);
            Ar[nxt][0] = *(const float4*)(arow + off);
            Ar[nxt][1] = *(const float4*)(arow + off + 4);
            const long bb = ((long)((kz * 16 + it + 1) * 16 + wv * 4) * 64 + lane) * 8;
#pragma unroll
            for (int j = 0; j < 4; ++j) {
                Bh[nxt][j] = *(const f16x8*)(Wth + bb + (long)j * 512);
                Bl[nxt][j] = *(const f16x8*)(Wtl + bb + (long)j * 512);
            }
        }
        __builtin_amdgcn_sched_barrier(0);

        // (b) cvt A(it) -> packed hi/lo (pkrtz), converted once per element
        {
            const float4 a0 = Ar[cur][0], a1 = Ar[cur][1];
            h16x2 h01 = __builtin_amdgcn_cvt_pkrtz(a0.x, a0.y);
            h16x2 h23 = __builtin_amdgcn_cvt_pkrtz(a0.z, a0.w);
            h16x2 h45 = __builtin_amdgcn_cvt_pkrtz(a1.x, a1.y);
            h16x2 h67 = __builtin_amdgcn_cvt_pkrtz(a1.z, a1.w);
            h16x2 l01 = __builtin_amdgcn_cvt_pkrtz(a0.x - (float)h01[0], a0.y - (float)h01[1]);
            h16x2 l23 = __builtin_amdgcn_cvt_pkrtz(a0.z - (float)h23[0], a0.w - (float)h23[1]);
            h16x2 l45 = __builtin_amdgcn_cvt_pkrtz(a1.x - (float)h45[0], a1.y - (float)h45[1]);
            h16x2 l67 = __builtin_amdgcn_cvt_pkrtz(a1.z - (float)h67[0], a1.w - (float)h67[1]);
            union { f16x8 v; h16x2 p[4]; } H, L;
            H.p[0] = h01; H.p[1] = h23; H.p[2] = h45; H.p[3] = h67;
            L.p[0] = l01; L.p[1] = l23; L.p[2] = l45; L.p[3] = l67;
            *(f16x8*)(wh + cur * 2048) = H.v;   // ds_write_b128
            *(f16x8*)(wl + cur * 2048) = L.v;   // ds_write_b128
        }
        asm volatile("s_waitcnt lgkmcnt(0)" ::: "memory");
        __builtin_amdgcn_sched_barrier(0);
        __builtin_amdgcn_s_barrier();           // buf[cur] fully written
        __builtin_amdgcn_sched_barrier(0);

        // (c) A-frag reads + MFMA (3 independent passes)
        f16x8 ah[4], al[4];
#pragma unroll
        for (int i = 0; i < 4; ++i) {
            ah[i] = *(const f16x8*)&Fh[cur][i][lane][0];
            al[i] = *(const f16x8*)&Fl[cur][i][lane][0];
        }
#pragma unroll
        for (int i = 0; i < 4; ++i)
#pragma unroll
            for (int j = 0; j < 4; ++j)
                acc[i][j] = __builtin_amdgcn_mfma_f32_16x16x32_f16(ah[i], Bh[cur][j], acc[i][j], 0, 0, 0);
#pragma unroll
        for (int i = 0; i < 4; ++i)
#pragma unroll
            for (int j = 0; j < 4; ++j)
                acc[i][j] = __builtin_amdgcn_mfma_f32_16x16x32_f16(al[i], Bh[cur][j], acc[i][j], 0, 0, 0);
#pragma unroll
        for (int i = 0; i < 4; ++i)
#pragma unroll
            for (int j = 0; j < 4; ++j)
                acc[i][j] = __builtin_amdgcn_mfma_f32_16x16x32_f16(ah[i], Bl[cur][j], acc[i][j], 0, 0, 0);
    }

    float* outp = tWpart + (long)kz * 524288;
#pragma unroll
    for (int i = 0; i < 4; ++i) {
        const int mbase = m0 + i * 16 + quad * 4;
#pragma unroll
        for (int j = 0; j < 4; ++j) {
            const int c = (wv * 4 + j) * 16 + l15;
#pragma unroll
            for (int rg = 0; rg < 4; ++rg)
                outp[(long)(mbase + rg) * 256 + c] = acc[i][j][rg];
        }
    }
}

// ---------------------------------------------------------------------------
// K2 v2: reduce split-K partials; logits = tW @ ctx[b]; softmax; write attnT.
// grid (64 b, 8 qg) x 256 thr. Block id = b + 64*qg -> XCD = b%8, so all 8
// qg-blocks of a batch share one XCD-L2 (ctx[b] fetched once per XCD).
// Phase 1: float4 z-reduce (16 x 16B loads/thread, deep MLP).
// Phase 2: 4 independent FMA chains (c split in halves), unroll 8.
// ---------------------------------------------------------------------------
__global__ __launch_bounds__(256) void k2_logits_softmax(const float* __restrict__ tWpart,
                                                         const float* __restrict__ ctx,
                                                         float* __restrict__ attnT) {
    const int b  = blockIdx.x;      // 0..63  (fast dim -> XCD = b%8)
    const int qg = blockIdx.y;      // 0..7
    const int t  = threadIdx.x;
    __shared__ float tw4[4][256];
    {
        const int q = t >> 6;               // 0..3
        const int c4 = (t & 63) * 4;        // 0..252
        const float* p = tWpart + (long)(b * 32 + qg * 4 + q) * 256 + c4;
        float4 s = make_float4(0.f, 0.f, 0.f, 0.f);
#pragma unroll
        for (int z = 0; z < ZK; ++z) {
            float4 v = *(const float4*)(p + (long)z * 524288);
            s.x += v.x; s.y += v.y; s.z += v.z; s.w += v.w;
        }
        *(float4*)&tw4[q][c4] = s;
    }
    __syncthreads();
    const int q = t >> 6, lane = t & 63;
    const float* ctxb = ctx + (long)b * 32768 + lane * 2;
    float ax0 = 0.f, ay0 = 0.f, ax1 = 0.f, ay1 = 0.f;
#pragma unroll 8
    for (int c = 0; c < 128; ++c) {
        float twa = tw4[q][c];
        float twb = tw4[q][c + 128];
        float2 cva = *(const float2*)(ctxb + c * 128);
        float2 cvb = *(const float2*)(ctxb + (c + 128) * 128);
        ax0 = fmaf(twa, cva.x, ax0);
        ay0 = fmaf(twa, cva.y, ay0);
        ax1 = fmaf(twb, cvb.x, ax1);
        ay1 = fmaf(twb, cvb.y, ay1);
    }
    float ax = ax0 + ax1, ay = ay0 + ay1;
    float mx = fmaxf(ax, ay);
#pragma unroll
    for (int m = 1; m <= 32; m <<= 1) mx = fmaxf(mx, __shfl_xor(mx, m));
    float ex = expf(ax - mx);
    float ey = expf(ay - mx);
    float sm = ex + ey;
#pragma unroll
    for (int m = 1; m <= 32; m <<= 1) sm += __shfl_xor(sm, m);
    float inv = 1.f / sm;
    ex *= inv; ey *= inv;
    float* o = attnT + (long)b * 4096 + (qg * 4 + q);
    o[(lane * 2 + 0) * 32] = ex;
    o[(lane * 2 + 1) * 32] = ey;
}

// ---------------------------------------------------------------------------
// K3: ctxAqf (frag-major fp16) = ctx @ attn. grid (8 c-chunks, 64 b) x 256.
// Frag addr: [((n>>4)*8 + (c>>5))*64 + (n&15) + 16*((c>>3)&3)]*8 + (c&7)
// ---------------------------------------------------------------------------
__global__ __launch_bounds__(256) void k3_ctxA(const float* __restrict__ ctx,
                                               const float* __restrict__ attnT,
                                               _Float16* __restrict__ ctxAqf) {
    const int cg = blockIdx.x;      // c-chunk of 32
    const int b  = blockIdx.y;
    const int t  = threadIdx.x;
    __shared__ float at[128][32];
    __shared__ float cs[32][132];
#pragma unroll
    for (int i = 0; i < 4; ++i)
        *(float4*)((float*)at + i * 1024 + t * 4) =
            *(const float4*)(attnT + (long)b * 4096 + i * 1024 + t * 4);
#pragma unroll
    for (int i = 0; i < 4; ++i) {
        int idx = i * 256 + t;
        int c = idx >> 5, sseg = (idx & 31) * 4;
        *(float4*)&cs[c][sseg] = *(const float4*)(ctx + (long)b * 32768 + (long)(cg * 32 + c) * 128 + sseg);
    }
    __syncthreads();
    const int c = t >> 3;           // 0..31 (local)
    const int qs = (t & 7) * 4;     // 4 q's
    float4 acc = make_float4(0.f, 0.f, 0.f, 0.f);
#pragma unroll 4
    for (int s = 0; s < 128; ++s) {
        float cv = cs[c][s];
        float4 av = *(const float4*)&at[s][qs];
        acc.x = fmaf(cv, av.x, acc.x);
        acc.y = fmaf(cv, av.y, acc.y);
        acc.z = fmaf(cv, av.z, acc.z);
        acc.w = fmaf(cv, av.w, acc.w);
    }
    const int cglob = cg * 32 + c;
    const long cpart = (long)(cglob >> 5) * 64 + 16 * ((cglob >> 3) & 3);
    float vals[4] = {acc.x, acc.y, acc.z, acc.w};
#pragma unroll
    for (int u = 0; u < 4; ++u) {
        int n = b * 32 + qs + u;
        long addr = ((long)(n >> 4) * 8 * 64 + cpart + (n & 15)) * 8 + (cglob & 7);
        ctxAqf[addr] = (_Float16)vals[u];
    }
}

// ---------------------------------------------------------------------------
// K4 v2: wc = W @ ctxA. grid (128, 16) x 256 thr (4 waves).
// B-panel = 64 contiguous frags (64 KB) of ctxAqf, staged to LDS ONCE per
// block via global_load_lds. Wave tile: 16 m x 128 n. K=256 (8 kb of 32).
// ---------------------------------------------------------------------------
__global__ __launch_bounds__(256) void k4_mfma(const _Float16* __restrict__ Wbf,
                                               const _Float16* __restrict__ ctxAqf,
                                               float* __restrict__ out0) {
    const int t = threadIdx.x;
    const int lane = t & 63, wv = t >> 6;
    const int mb = blockIdx.x * 4 + wv;     // 0..511 (16 d-rows each)
    const int nb0 = blockIdx.y * 8;         // 8 nb groups of 16 n

    __shared__ _Float16 Bs[32768];          // 64 KB: frags [nb0*8 .. nb0*8+64)

    {
        const _Float16* gsrc = ctxAqf + (long)nb0 * 4096;
#pragma unroll
        for (int i = 0; i < 16; ++i) {
            const int chunk = i * 256 + wv * 64;            // wave-uniform
            GLDS16(gsrc + (long)chunk * 8 + lane * 8, Bs + chunk * 8);
        }
    }
    __syncthreads();

    const _Float16* abase = Wbf + ((long)mb * 8 * 64 + lane) * 8;

    f32x4 acc[8];
#pragma unroll
    for (int j = 0; j < 8; ++j) acc[j] = (f32x4){0.f, 0.f, 0.f, 0.f};

#pragma unroll
    for (int kb = 0; kb < 8; ++kb) {
        f16x8 af = *(const f16x8*)(abase + (long)kb * 512);
#pragma unroll
        for (int j = 0; j < 8; ++j) {
            f16x8 bf = *(const f16x8*)(Bs + (j * 8 + kb) * 512 + lane * 8);
            acc[j] = __builtin_amdgcn_mfma_f32_16x16x32_f16(af, bf, acc[j], 0, 0, 0);
        }
    }
    const int quad = lane >> 4, col = lane & 15;
#pragma unroll
    for (int j = 0; j < 8; ++j) {
        const int n = (nb0 + j) * 16 + col;
        float* ob = out0 + (long)(n >> 5) * 262144 + (n & 31);
#pragma unroll
        for (int rg = 0; rg < 4; ++rg) {
            const int d = mb * 16 + quad * 4 + rg;
            ob[(long)((d >> 3) & 31) * 8192 + (long)(d >> 8) * 256 + (long)(d & 7) * 32] = acc[j][rg];
        }
    }
}

// ---------------------------------------------------------------------------
extern "C" void kernel_launch(void* const* d_in, const int* in_sizes, int n_in,
                              void* d_out, int out_size, void* d_ws, size_t ws_size,
                              hipStream_t stream) {
    const float* inp = (const float*)d_in[0];
    const float* ctx = (const float*)d_in[1];
    const float* Wm  = (const float*)d_in[2];
    float* out0 = (float*)d_out;
    float* out1 = out0 + 16777216;

    // Workspace layout (40 MB peak):
    //   [0, 32 MB)   : tWpart (k1->k2); after k2, overlaid by Wbf (4 MB) + ctxAqf (1 MB)
    //   [32, 36 MB)  : Wth
    //   [36, 40 MB)  : Wtl
    float* wsf = (float*)d_ws;
    float* tWpart = wsf;                                   // 16*2048*256 floats = 32 MB
    _Float16* Wbf    = (_Float16*)wsf;                     // overlaid after k2 (4 MB)
    _Float16* ctxAqf = (_Float16*)(wsf + 1048576);         // overlaid after k2 (1 MB)
    _Float16* Wth = (_Float16*)(wsf + 8388608);            // 4 MB
    _Float16* Wtl = Wth + 2097152;                         // 4 MB

    hipLaunchKernelGGL(k0a_prep, dim3(256), dim3(256), 0, stream, Wm, Wth, Wtl);
    hipLaunchKernelGGL(k1_mfma, dim3(16, 32), dim3(256), 0, stream, inp, Wth, Wtl, tWpart);
    hipLaunchKernelGGL(k2_logits_softmax, dim3(64, 8), dim3(256), 0, stream, tWpart, ctx, out1);
    hipLaunchKernelGGL(k0b_prep, dim3(1024), dim3(256), 0, stream, Wm, Wbf);
    hipLaunchKernelGGL(k3_ctxA, dim3(8, 64), dim3(256), 0, stream, ctx, out1, ctxAqf);
    hipLaunchKernelGGL(k4_mfma, dim3(128, 16), dim3(256), 0, stream, Wbf, ctxAqf, out0);
}

// Round 7
// 196.011 us; speedup vs baseline: 1.2553x; 1.0022x over previous
//
#include <hip/hip_runtime.h>
#include <math.h>

// B=64, CLN=32, QL=32, IH=16, IW=16, IDF=8192, CDF=256, SL=128
// input : [64][32][32][16][16] fp32 ; context:[64][256][128] fp32 ; W:[8192][256] fp32
// out0: wc fp32 (16777216) ; out1: attnT [64][128][32] fp32 (262144)
//
// k1 v6: 2-deep A register pipeline (cvt A(it+1) overlaps MFMA(it)); single
//        s_barrier/iter with write-after-barrier schedule; counted waits only
//        (no vmcnt(0) in loop); s_setprio around MFMA cluster.
// k2 v3: tWpart z-slice stride padded +4352B (breaks 2MB power-of-2 HBM
//        channel aliasing) when workspace allows; stride is a kernel arg.
// k0  : merged k0a+k0b single launch (big-ws path).
// Host picks layout by ws_size: big (47.3 MB, padded + no overlay, 5 launches)
// or legacy (40 MB, overlay, 6 launches).

#define ZK 16

typedef _Float16 f16x8 __attribute__((ext_vector_type(8)));
typedef __fp16 h16x2 __attribute__((ext_vector_type(2)));
typedef float f32x4 __attribute__((ext_vector_type(4)));

#define GLDS16(gp, lp)                                                          \
    __builtin_amdgcn_global_load_lds(                                           \
        (const __attribute__((address_space(1))) void*)(gp),                    \
        (__attribute__((address_space(3))) void*)(lp), 16, 0, 0)

// ---------------------------------------------------------------------------
// K0a body: W -> Wth/Wtl (k1 B-operand hi/lo, frag-major).
// Frag addr: ((kb*16+nsub)*64 + lane)*8 ; lane=(c&15)+16*((k>>3)&3), j=k&7
// ---------------------------------------------------------------------------
__device__ __forceinline__ void k0a_body(const float* __restrict__ Wm,
                                         _Float16* __restrict__ Wth,
                                         _Float16* __restrict__ Wtl,
                                         int kb, int t, float (*tile)[260]) {
    {
        const int r = t >> 3;           // 0..31
        const int c0 = (t & 7) * 32;    // 0..224
        const float* src = Wm + (long)(kb * 32 + r) * 256 + c0;
#pragma unroll
        for (int i = 0; i < 8; ++i) {
            float4 v = *(const float4*)(src + i * 4);
            tile[r][c0 + i * 4 + 0] = v.x;
            tile[r][c0 + i * 4 + 1] = v.y;
            tile[r][c0 + i * 4 + 2] = v.z;
            tile[r][c0 + i * 4 + 3] = v.w;
        }
    }
    __syncthreads();
    const int lane = t & 63;
    const int quad = lane >> 4, l15 = lane & 15;
#pragma unroll
    for (int i = 0; i < 4; ++i) {
        int nsub = (t >> 6) * 4 + i;    // 0..15
        f16x8 oh, ol;
#pragma unroll
        for (int j = 0; j < 8; ++j) {
            float f = tile[quad * 8 + j][nsub * 16 + l15];
            _Float16 h = (_Float16)f;
            oh[j] = h;
            ol[j] = (_Float16)(f - (float)h);
        }
        long addr = ((long)(kb * 16 + nsub) * 64 + lane) * 8;
        *(f16x8*)(Wth + addr) = oh;
        *(f16x8*)(Wtl + addr) = ol;
    }
}

// ---------------------------------------------------------------------------
// K0b body: W -> Wbf (k4 A-operand fp16, frag-major).
// Frag addr: ((mb*8+kb4)*64+lane)*8 ; lane=(d&15)+16*((c>>3)&3), j=c&7
// ---------------------------------------------------------------------------
__device__ __forceinline__ void k0b_body(const float* __restrict__ Wm,
                                         _Float16* __restrict__ Wbf,
                                         int bx, int t) {
    const int fid = bx * 4 + (t >> 6);   // 0..4095
    const int mb = fid >> 3, kb4 = fid & 7;
    const int lane = t & 63;
    const int quad = lane >> 4, l15 = lane & 15;
    const float* src = Wm + (long)(mb * 16 + l15) * 256 + kb4 * 32 + quad * 8;
    float4 u0 = *(const float4*)(src);
    float4 u1 = *(const float4*)(src + 4);
    f16x8 o;
    o[0] = (_Float16)u0.x; o[1] = (_Float16)u0.y;
    o[2] = (_Float16)u0.z; o[3] = (_Float16)u0.w;
    o[4] = (_Float16)u1.x; o[5] = (_Float16)u1.y;
    o[6] = (_Float16)u1.z; o[7] = (_Float16)u1.w;
    *(f16x8*)(Wbf + ((long)fid * 64 + lane) * 8) = o;
}

// Legacy separate kernels
__global__ __launch_bounds__(256) void k0a_prep(const float* __restrict__ Wm,
                                                _Float16* __restrict__ Wth,
                                                _Float16* __restrict__ Wtl) {
    __shared__ float tile[32][260];
    k0a_body(Wm, Wth, Wtl, blockIdx.x, threadIdx.x, tile);
}
__global__ __launch_bounds__(256) void k0b_prep(const float* __restrict__ Wm,
                                                _Float16* __restrict__ Wbf) {
    k0b_body(Wm, Wbf, blockIdx.x, threadIdx.x);
}
// Merged kernel (big-ws path): blocks 0..255 -> k0a, 256..1279 -> k0b
__global__ __launch_bounds__(256) void k0_all(const float* __restrict__ Wm,
                                              _Float16* __restrict__ Wth,
                                              _Float16* __restrict__ Wtl,
                                              _Float16* __restrict__ Wbf) {
    __shared__ float tile[32][260];
    if (blockIdx.x < 256) k0a_body(Wm, Wth, Wtl, blockIdx.x, threadIdx.x, tile);
    else                  k0b_body(Wm, Wbf, blockIdx.x - 256, threadIdx.x);
}

// ---------------------------------------------------------------------------
// K1 v6: tWpart = targetT @ W, fp16 hi/lo 3-pass.
// grid (16 kz, 32 m-tiles of 64) x 256 thr (4 waves; wave tile 64m x 64n).
// 2 blocks/CU. A: 2-deep register pipeline -> cvt -> f16 LDS dbuf.
// Schedule per iter: issue A(it+2)+B(it+1) | cvt A(it+1) | s_barrier |
//   ds_write A(it+1)->buf[nxt] | ds_read buf[cur] | lgkmcnt(0) | 48 MFMA.
// Race-freedom with ONE barrier/iter: reads of buf[nxt] (at it-1) complete
// before each wave's lgkmcnt(0)@it-1, hence before barrier(it) -> write safe;
// writes@it complete before each wave's lgkmcnt(0)@it, hence before
// barrier(it+1) -> reads@it+1 safe.
// ---------------------------------------------------------------------------
__global__ __launch_bounds__(256, 2) void k1_mfma(const float* __restrict__ inp,
                                                  const _Float16* __restrict__ Wth,
                                                  const _Float16* __restrict__ Wtl,
                                                  float* __restrict__ tWpart,
                                                  const long zstride) {
    const int kz = blockIdx.x;          // 0..15
    const int m0 = blockIdx.y * 64;     // 32 m-tiles of 64 rows
    const int t = threadIdx.x;
    const int lane = t & 63, wv = t >> 6;
    const int quad = lane >> 4, l15 = lane & 15;

    __shared__ _Float16 Fh[2][4][64][8];    // 8 KB
    __shared__ _Float16 Fl[2][4][64][8];    // 8 KB

    const float* arow;
    {
        const int mA = m0 + (t >> 2);
        arow = inp + (long)(mA >> 5) * 262144 + (long)(mA & 31) * 256 + (t & 3) * 8;
    }
    _Float16* wh = &Fh[0][t >> 6][((t & 3) << 4) | ((t >> 2) & 15)][0];
    _Float16* wl = &Fl[0][t >> 6][((t & 3) << 4) | ((t >> 2) & 15)][0];

    f32x4 acc[4][4];
#pragma unroll
    for (int i = 0; i < 4; ++i)
#pragma unroll
        for (int j = 0; j < 4; ++j) acc[i][j] = (f32x4){0.f, 0.f, 0.f, 0.f};

    float4 Ar[2][2];                    // Ar[it&1] holds A(it)
    f16x8 Bh[2][4], Bl[2][4];

#define AOFF(kg) ((long)((kg) >> 8) * 8192 + ((kg) & 255))
#define CVTHL(a0, a1, H, L)                                                     \
    {                                                                           \
        h16x2 h01 = __builtin_amdgcn_cvt_pkrtz(a0.x, a0.y);                     \
        h16x2 h23 = __builtin_amdgcn_cvt_pkrtz(a0.z, a0.w);                     \
        h16x2 h45 = __builtin_amdgcn_cvt_pkrtz(a1.x, a1.y);                     \
        h16x2 h67 = __builtin_amdgcn_cvt_pkrtz(a1.z, a1.w);                     \
        h16x2 l01 = __builtin_amdgcn_cvt_pkrtz(a0.x - (float)h01[0], a0.y - (float)h01[1]); \
        h16x2 l23 = __builtin_amdgcn_cvt_pkrtz(a0.z - (float)h23[0], a0.w - (float)h23[1]); \
        h16x2 l45 = __builtin_amdgcn_cvt_pkrtz(a1.x - (float)h45[0], a1.y - (float)h45[1]); \
        h16x2 l67 = __builtin_amdgcn_cvt_pkrtz(a1.z - (float)h67[0], a1.w - (float)h67[1]); \
        union { f16x8 v; h16x2 p[4]; } U, V;                                    \
        U.p[0] = h01; U.p[1] = h23; U.p[2] = h45; U.p[3] = h67;                 \
        V.p[0] = l01; V.p[1] = l23; V.p[2] = l45; V.p[3] = l67;                 \
        H = U.v; L = V.v;                                                       \
    }

    // ---- prologue: issue A(0),A(1),B(0); cvt+write A(0) -> buf0
    {
        const int kg0 = kz * 512;
        Ar[0][0] = *(const float4*)(arow + AOFF(kg0));
        Ar[0][1] = *(const float4*)(arow + AOFF(kg0) + 4);
        const int kg1 = kg0 + 32;
        Ar[1][0] = *(const float4*)(arow + AOFF(kg1));
        Ar[1][1] = *(const float4*)(arow + AOFF(kg1) + 4);
        const long bb = ((long)((kz * 16) * 16 + wv * 4) * 64 + lane) * 8;
#pragma unroll
        for (int j = 0; j < 4; ++j) {
            Bh[0][j] = *(const f16x8*)(Wth + bb + (long)j * 512);
            Bl[0][j] = *(const f16x8*)(Wtl + bb + (long)j * 512);
        }
        f16x8 H0, L0;
        const float4 a0 = Ar[0][0], a1 = Ar[0][1];
        CVTHL(a0, a1, H0, L0);
        *(f16x8*)(wh) = H0;             // buf 0
        *(f16x8*)(wl) = L0;
        asm volatile("s_waitcnt lgkmcnt(0)" ::: "memory");
        __builtin_amdgcn_sched_barrier(0);
    }

#pragma unroll
    for (int it = 0; it < 16; ++it) {
        const int cur = it & 1, nxt = cur ^ 1;
        // (a) issue A(it+2) -> Ar[cur] (slot free: A(it) cvt'd at it-1)
        if (it < 14) {
            const int kg = kz * 512 + (it + 2) * 32;
            Ar[cur][0] = *(const float4*)(arow + AOFF(kg));
            Ar[cur][1] = *(const float4*)(arow + AOFF(kg) + 4);
        }
        // (b) issue B(it+1)
        if (it < 15) {
            const long bb = ((long)((kz * 16 + it + 1) * 16 + wv * 4) * 64 + lane) * 8;
#pragma unroll
            for (int j = 0; j < 4; ++j) {
                Bh[nxt][j] = *(const f16x8*)(Wth + bb + (long)j * 512);
                Bl[nxt][j] = *(const f16x8*)(Wtl + bb + (long)j * 512);
            }
        }
        __builtin_amdgcn_sched_barrier(0);
        // (c) cvt A(it+1) (loaded at it-1) while others still run MFMA(it-1)
        f16x8 Hn, Ln;
        if (it < 15) {
            const float4 a0 = Ar[nxt][0], a1 = Ar[nxt][1];
            CVTHL(a0, a1, Hn, Ln);
        }
        __builtin_amdgcn_sched_barrier(0);
        __builtin_amdgcn_s_barrier();       // buf[nxt] free for rewrite
        // (d) ds_write A(it+1) -> buf[nxt]
        if (it < 15) {
            *(f16x8*)(wh + nxt * 2048) = Hn;
            *(f16x8*)(wl + nxt * 2048) = Ln;
        }
        // (e) ds_read buf[cur]
        f16x8 ah[4], al[4];
#pragma unroll
        for (int i = 0; i < 4; ++i) {
            ah[i] = *(const f16x8*)&Fh[cur][i][lane][0];
            al[i] = *(const f16x8*)&Fl[cur][i][lane][0];
        }
        asm volatile("s_waitcnt lgkmcnt(0)" ::: "memory");
        __builtin_amdgcn_sched_barrier(0);
        // (f) MFMA (3 independent passes)
        __builtin_amdgcn_s_setprio(1);
#pragma unroll
        for (int i = 0; i < 4; ++i)
#pragma unroll
            for (int j = 0; j < 4; ++j)
                acc[i][j] = __builtin_amdgcn_mfma_f32_16x16x32_f16(ah[i], Bh[cur][j], acc[i][j], 0, 0, 0);
#pragma unroll
        for (int i = 0; i < 4; ++i)
#pragma unroll
            for (int j = 0; j < 4; ++j)
                acc[i][j] = __builtin_amdgcn_mfma_f32_16x16x32_f16(al[i], Bh[cur][j], acc[i][j], 0, 0, 0);
#pragma unroll
        for (int i = 0; i < 4; ++i)
#pragma unroll
            for (int j = 0; j < 4; ++j)
                acc[i][j] = __builtin_amdgcn_mfma_f32_16x16x32_f16(ah[i], Bl[cur][j], acc[i][j], 0, 0, 0);
        __builtin_amdgcn_s_setprio(0);
    }

    float* outp = tWpart + (long)kz * zstride;
#pragma unroll
    for (int i = 0; i < 4; ++i) {
        const int mbase = m0 + i * 16 + quad * 4;
#pragma unroll
        for (int j = 0; j < 4; ++j) {
            const int c = (wv * 4 + j) * 16 + l15;
#pragma unroll
            for (int rg = 0; rg < 4; ++rg)
                outp[(long)(mbase + rg) * 256 + c] = acc[i][j][rg];
        }
    }
}

// ---------------------------------------------------------------------------
// K2 v3: reduce split-K partials; logits = tW @ ctx[b]; softmax; write attnT.
// grid (64 b, 8 qg) x 256 thr. XCD = b%8 -> ctx[b] L2-resident per XCD.
// zstride arg: padded (+1088 floats) slice stride breaks the 2MB power-of-2
// HBM channel aliasing of the z-reduce.
// ---------------------------------------------------------------------------
__global__ __launch_bounds__(256) void k2_logits_softmax(const float* __restrict__ tWpart,
                                                         const float* __restrict__ ctx,
                                                         float* __restrict__ attnT,
                                                         const long zstride) {
    const int b  = blockIdx.x;      // 0..63  (fast dim -> XCD = b%8)
    const int qg = blockIdx.y;      // 0..7
    const int t  = threadIdx.x;
    __shared__ float tw4[4][256];
    {
        const int q = t >> 6;               // 0..3
        const int c4 = (t & 63) * 4;        // 0..252
        const float* p = tWpart + (long)(b * 32 + qg * 4 + q) * 256 + c4;
        float4 s = make_float4(0.f, 0.f, 0.f, 0.f);
#pragma unroll
        for (int z = 0; z < ZK; ++z) {
            float4 v = *(const float4*)(p + (long)z * zstride);
            s.x += v.x; s.y += v.y; s.z += v.z; s.w += v.w;
        }
        *(float4*)&tw4[q][c4] = s;
    }
    __syncthreads();
    const int q = t >> 6, lane = t & 63;
    const float* ctxb = ctx + (long)b * 32768 + lane * 2;
    float ax0 = 0.f, ay0 = 0.f, ax1 = 0.f, ay1 = 0.f;
#pragma unroll 8
    for (int c = 0; c < 128; ++c) {
        float twa = tw4[q][c];
        float twb = tw4[q][c + 128];
        float2 cva = *(const float2*)(ctxb + c * 128);
        float2 cvb = *(const float2*)(ctxb + (c + 128) * 128);
        ax0 = fmaf(twa, cva.x, ax0);
        ay0 = fmaf(twa, cva.y, ay0);
        ax1 = fmaf(twb, cvb.x, ax1);
        ay1 = fmaf(twb, cvb.y, ay1);
    }
    float ax = ax0 + ax1, ay = ay0 + ay1;
    float mx = fmaxf(ax, ay);
#pragma unroll
    for (int m = 1; m <= 32; m <<= 1) mx = fmaxf(mx, __shfl_xor(mx, m));
    float ex = expf(ax - mx);
    float ey = expf(ay - mx);
    float sm = ex + ey;
#pragma unroll
    for (int m = 1; m <= 32; m <<= 1) sm += __shfl_xor(sm, m);
    float inv = 1.f / sm;
    ex *= inv; ey *= inv;
    float* o = attnT + (long)b * 4096 + (qg * 4 + q);
    o[(lane * 2 + 0) * 32] = ex;
    o[(lane * 2 + 1) * 32] = ey;
}

// ---------------------------------------------------------------------------
// K3: ctxAqf (frag-major fp16) = ctx @ attn. grid (8 c-chunks, 64 b) x 256.
// ---------------------------------------------------------------------------
__global__ __launch_bounds__(256) void k3_ctxA(const float* __restrict__ ctx,
                                               const float* __restrict__ attnT,
                                               _Float16* __restrict__ ctxAqf) {
    const int cg = blockIdx.x;      // c-chunk of 32
    const int b  = blockIdx.y;
    const int t  = threadIdx.x;
    __shared__ float at[128][32];
    __shared__ float cs[32][132];
#pragma unroll
    for (int i = 0; i < 4; ++i)
        *(float4*)((float*)at + i * 1024 + t * 4) =
            *(const float4*)(attnT + (long)b * 4096 + i * 1024 + t * 4);
#pragma unroll
    for (int i = 0; i < 4; ++i) {
        int idx = i * 256 + t;
        int c = idx >> 5, sseg = (idx & 31) * 4;
        *(float4*)&cs[c][sseg] = *(const float4*)(ctx + (long)b * 32768 + (long)(cg * 32 + c) * 128 + sseg);
    }
    __syncthreads();
    const int c = t >> 3;           // 0..31 (local)
    const int qs = (t & 7) * 4;     // 4 q's
    float4 acc = make_float4(0.f, 0.f, 0.f, 0.f);
#pragma unroll 4
    for (int s = 0; s < 128; ++s) {
        float cv = cs[c][s];
        float4 av = *(const float4*)&at[s][qs];
        acc.x = fmaf(cv, av.x, acc.x);
        acc.y = fmaf(cv, av.y, acc.y);
        acc.z = fmaf(cv, av.z, acc.z);
        acc.w = fmaf(cv, av.w, acc.w);
    }
    const int cglob = cg * 32 + c;
    const long cpart = (long)(cglob >> 5) * 64 + 16 * ((cglob >> 3) & 3);
    float vals[4] = {acc.x, acc.y, acc.z, acc.w};
#pragma unroll
    for (int u = 0; u < 4; ++u) {
        int n = b * 32 + qs + u;
        long addr = ((long)(n >> 4) * 8 * 64 + cpart + (n & 15)) * 8 + (cglob & 7);
        ctxAqf[addr] = (_Float16)vals[u];
    }
}

// ---------------------------------------------------------------------------
// K4 v2: wc = W @ ctxA. grid (128, 16) x 256 thr (4 waves).
// B-panel (64 KB contiguous ctxAqf slice) staged to LDS once per block.
// ---------------------------------------------------------------------------
__global__ __launch_bounds__(256) void k4_mfma(const _Float16* __restrict__ Wbf,
                                               const _Float16* __restrict__ ctxAqf,
                                               float* __restrict__ out0) {
    const int t = threadIdx.x;
    const int lane = t & 63, wv = t >> 6;
    const int mb = blockIdx.x * 4 + wv;     // 0..511 (16 d-rows each)
    const int nb0 = blockIdx.y * 8;         // 8 nb groups of 16 n

    __shared__ _Float16 Bs[32768];          // 64 KB

    {
        const _Float16* gsrc = ctxAqf + (long)nb0 * 4096;
#pragma unroll
        for (int i = 0; i < 16; ++i) {
            const int chunk = i * 256 + wv * 64;            // wave-uniform
            GLDS16(gsrc + (long)chunk * 8 + lane * 8, Bs + chunk * 8);
        }
    }
    __syncthreads();

    const _Float16* abase = Wbf + ((long)mb * 8 * 64 + lane) * 8;

    f32x4 acc[8];
#pragma unroll
    for (int j = 0; j < 8; ++j) acc[j] = (f32x4){0.f, 0.f, 0.f, 0.f};

#pragma unroll
    for (int kb = 0; kb < 8; ++kb) {
        f16x8 af = *(const f16x8*)(abase + (long)kb * 512);
#pragma unroll
        for (int j = 0; j < 8; ++j) {
            f16x8 bf = *(const f16x8*)(Bs + (j * 8 + kb) * 512 + lane * 8);
            acc[j] = __builtin_amdgcn_mfma_f32_16x16x32_f16(af, bf, acc[j], 0, 0, 0);
        }
    }
    const int quad = lane >> 4, col = lane & 15;
#pragma unroll
    for (int j = 0; j < 8; ++j) {
        const int n = (nb0 + j) * 16 + col;
        float* ob = out0 + (long)(n >> 5) * 262144 + (n & 31);
#pragma unroll
        for (int rg = 0; rg < 4; ++rg) {
            const int d = mb * 16 + quad * 4 + rg;
            ob[(long)((d >> 3) & 31) * 8192 + (long)(d >> 8) * 256 + (long)(d & 7) * 32] = acc[j][rg];
        }
    }
}

// ---------------------------------------------------------------------------
extern "C" void kernel_launch(void* const* d_in, const int* in_sizes, int n_in,
                              void* d_out, int out_size, void* d_ws, size_t ws_size,
                              hipStream_t stream) {
    const float* inp = (const float*)d_in[0];
    const float* ctx = (const float*)d_in[1];
    const float* Wm  = (const float*)d_in[2];
    float* out0 = (float*)d_out;
    float* out1 = out0 + 16777216;

    char* wsb = (char*)d_ws;
    const size_t BIG_NEED = 47255552ull;    // padded tWpart + Wth + Wtl + Wbf + ctxAqf

    if (ws_size >= BIG_NEED) {
        // Big-ws layout (47.3 MB), no overlays, padded z-stride:
        //   tWpart: [0, 33,624,064)            16 slices of (524288+1088) floats
        //   Wth   : [33,624,064, +4 MB)
        //   Wtl   : [37,818,368, +4 MB)
        //   Wbf   : [42,012,672, +4 MB)
        //   ctxAqf: [46,206,976, +1 MB)
        const long zs = 524288 + 1088;
        float*    tWpart = (float*)wsb;
        _Float16* Wth    = (_Float16*)(wsb + 33624064);
        _Float16* Wtl    = (_Float16*)(wsb + 37818368);
        _Float16* Wbf    = (_Float16*)(wsb + 42012672);
        _Float16* ctxAqf = (_Float16*)(wsb + 46206976);

        hipLaunchKernelGGL(k0_all, dim3(1280), dim3(256), 0, stream, Wm, Wth, Wtl, Wbf);
        hipLaunchKernelGGL(k1_mfma, dim3(16, 32), dim3(256), 0, stream, inp, Wth, Wtl, tWpart, zs);
        hipLaunchKernelGGL(k2_logits_softmax, dim3(64, 8), dim3(256), 0, stream, tWpart, ctx, out1, zs);
        hipLaunchKernelGGL(k3_ctxA, dim3(8, 64), dim3(256), 0, stream, ctx, out1, ctxAqf);
        hipLaunchKernelGGL(k4_mfma, dim3(128, 16), dim3(256), 0, stream, Wbf, ctxAqf, out0);
    } else {
        // Legacy 40 MB layout (overlaid):
        //   [0, 32 MB)  : tWpart ; after k2 overlaid by Wbf (4 MB) + ctxAqf (1 MB)
        //   [32, 36 MB) : Wth ; [36, 40 MB) : Wtl
        const long zs = 524288;
        float* wsf = (float*)d_ws;
        float*    tWpart = wsf;
        _Float16* Wbf    = (_Float16*)wsf;
        _Float16* ctxAqf = (_Float16*)(wsf + 1048576);
        _Float16* Wth    = (_Float16*)(wsf + 8388608);
        _Float16* Wtl    = Wth + 2097152;

        hipLaunchKernelGGL(k0a_prep, dim3(256), dim3(256), 0, stream, Wm, Wth, Wtl);
        hipLaunchKernelGGL(k1_mfma, dim3(16, 32), dim3(256), 0, stream, inp, Wth, Wtl, tWpart, zs);
        hipLaunchKernelGGL(k2_logits_softmax, dim3(64, 8), dim3(256), 0, stream, tWpart, ctx, out1, zs);
        hipLaunchKernelGGL(k0b_prep, dim3(1024), dim3(256), 0, stream, Wm, Wbf);
        hipLaunchKernelGGL(k3_ctxA, dim3(8, 64), dim3(256), 0, stream, ctx, out1, ctxAqf);
        hipLaunchKernelGGL(k4_mfma, dim3(128, 16), dim3(256), 0, stream, Wbf, ctxAqf, out0);
    }
}